// Round 22
// baseline (161.374 us; speedup 1.0000x reference)
//
#include <hip/hip_runtime.h>
#include <math.h>
#include <float.h>

#define B   256
#define D   256
#define D1  1024
#define D2  512
#define D3  256
#define NDIST (D1 + D2 + D3)   // 1792
#define CQ  2.0f               // qV2 static scale multiplier (step = sa[d]*CQ)

typedef __attribute__((ext_vector_type(8))) short short8;
typedef __attribute__((ext_vector_type(4))) float f32x4;
typedef __attribute__((ext_vector_type(4))) int   i32x4;

__device__ __forceinline__ float waveReduceSum(float v) {
    #pragma unroll
    for (int off = 32; off > 0; off >>= 1)
        v += __shfl_down(v, off, 64);
    return v;
}
__device__ __forceinline__ float waveReduceMax(float v) {
    #pragma unroll
    for (int off = 32; off > 0; off >>= 1)
        v = fmaxf(v, __shfl_down(v, off, 64));
    return v;
}
__device__ __forceinline__ unsigned short f2bf(float f) {
    unsigned int u = __float_as_uint(f);
    u = (u + 0x7FFFu + ((u >> 16) & 1u)) >> 16;   // RNE
    return (unsigned short)u;
}
__device__ __forceinline__ float bf2f(unsigned short h) {
    return __uint_as_float(((unsigned int)h) << 16);
}
__device__ __forceinline__ void gld16(const void* g, void* l) {
    __builtin_amdgcn_global_load_lds(
        (const __attribute__((address_space(1))) unsigned int*)g,
        (__attribute__((address_space(3))) unsigned int*)l, 16, 0, 0);
}
__device__ __forceinline__ int swz_src(int row, int lane) {
    return ((lane & 3) + ((row >> 1) & 3)) & 3;
}
__device__ __forceinline__ int swz_frag(int row, int quad) {
    return row * 32 + (((quad - ((row >> 1) & 3)) & 3) * 8);
}

// load 8 fp32, split to bf16 hi/lo short8
__device__ __forceinline__ void split8(const float* p, short8& h8, short8& l8) {
    float4 a = *(const float4*)(p);
    float4 b = *(const float4*)(p + 4);
    float hv[8] = { a.x, a.y, a.z, a.w, b.x, b.y, b.z, b.w };
    #pragma unroll
    for (int q = 0; q < 8; q++) {
        unsigned short hh = f2bf(hv[q]);
        h8[q] = (short)hh;
        l8[q] = (short)f2bf(hv[q] - bf2f(hh));
    }
}

// ---- compensated bf16 MFMA mainloop, 64x64 tile, K range [k0, k0+KL) -------
template <int KD, int KL>
__device__ __forceinline__ void mfma3_64(
    const unsigned short* __restrict__ Ahi, const unsigned short* __restrict__ Alo,
    const unsigned short* __restrict__ Bhi, const unsigned short* __restrict__ Blo,
    int m0, int n0, int k0, unsigned short* sm, f32x4 acc[2][2]) {
    int tid = threadIdx.x;
    int l = tid & 63, w = tid >> 6;
    int rsub = l >> 2;
    int quad = l >> 4, l16 = l & 15;
    int wm = (w >> 1) * 32, wn = (w & 1) * 32;
    unsigned short* sAh = sm;
    unsigned short* sAl = sm + 2048;
    unsigned short* sBh = sm + 4096;
    unsigned short* sBl = sm + 6144;
    ptrdiff_t dA = Alo - Ahi, dB = Blo - Bhi;
    int rloc = w * 16 + rsub;
    int c = swz_src(rloc, l);
    const unsigned short* pa = Ahi + (size_t)(m0 + rloc) * KD + k0 + c * 8;
    const unsigned short* pb = Bhi + (size_t)(n0 + rloc) * KD + k0 + c * 8;
    int aoff[2], boff[2];
    #pragma unroll
    for (int mt = 0; mt < 2; mt++) aoff[mt] = swz_frag(wm + mt * 16 + l16, quad);
    #pragma unroll
    for (int nt = 0; nt < 2; nt++) boff[nt] = swz_frag(wn + nt * 16 + l16, quad);
    for (int kk = 0; kk < KL; kk += 32) {
        gld16(pa + kk,      sAh + w * 512);
        gld16(pa + dA + kk, sAl + w * 512);
        gld16(pb + kk,      sBh + w * 512);
        gld16(pb + dB + kk, sBl + w * 512);
        __syncthreads();
        short8 ah[2], al[2], bh[2], bl[2];
        #pragma unroll
        for (int mt = 0; mt < 2; mt++) {
            ah[mt] = *(const short8*)(sAh + aoff[mt]);
            al[mt] = *(const short8*)(sAl + aoff[mt]);
        }
        #pragma unroll
        for (int nt = 0; nt < 2; nt++) {
            bh[nt] = *(const short8*)(sBh + boff[nt]);
            bl[nt] = *(const short8*)(sBl + boff[nt]);
        }
        #pragma unroll
        for (int mt = 0; mt < 2; mt++)
            #pragma unroll
            for (int nt = 0; nt < 2; nt++) {
                acc[mt][nt] = __builtin_amdgcn_mfma_f32_16x16x32_bf16(ah[mt], bh[nt], acc[mt][nt], 0, 0, 0);
                acc[mt][nt] = __builtin_amdgcn_mfma_f32_16x16x32_bf16(ah[mt], bl[nt], acc[mt][nt], 0, 0, 0);
                acc[mt][nt] = __builtin_amdgcn_mfma_f32_16x16x32_bf16(al[mt], bh[nt], acc[mt][nt], 0, 0, 0);
            }
        __syncthreads();
    }
}

// ---- dispatch 1: l1 gemm + zeros + fused quant+split jobs + rn1 ------------
__global__ __launch_bounds__(256) void k_l1p(
    const float* __restrict__ x, const float* __restrict__ W1,
    const float* __restrict__ W2, const float* __restrict__ W3,
    const float* __restrict__ b1,
    float* __restrict__ dists, unsigned char* __restrict__ m1q,
    unsigned short* __restrict__ h1hi, unsigned short* __restrict__ h1lo,
    float* __restrict__ zeros, float* __restrict__ outp,
    unsigned short* __restrict__ W2hi, unsigned short* __restrict__ W2lo,
    unsigned short* __restrict__ W3hi, unsigned short* __restrict__ W3lo,
    signed char* __restrict__ W1Ti8, float* __restrict__ saq,
    signed char* __restrict__ W2i8,  float* __restrict__ sbq,
    signed char* __restrict__ W3i8,  float* __restrict__ s3q,
    float* __restrict__ rn1) {
    __shared__ __align__(16) unsigned short sm[8192];
    int blk = blockIdx.x;
    int t = threadIdx.x;

    if (blk < 64) {          // l1: z1 GEMM; A=x, B=W1 staged fp32->hi/lo
        unsigned short* sAh = sm;
        unsigned short* sAl = sm + 2048;
        unsigned short* sBh = sm + 4096;
        unsigned short* sBl = sm + 6144;
        int m0 = (blk & 3) * 64, n0 = (blk >> 2) * 64;
        int l = t & 63, w = t >> 6;
        int rsub = l >> 2;
        int quad = l >> 4, l16 = l & 15;
        int wm = (w >> 1) * 32, wn = (w & 1) * 32;
        int rloc = w * 16 + rsub;
        int c = swz_src(rloc, l);
        const float* pax = x + (size_t)(m0 + rloc) * D + c * 8;
        const float* pbw = W1 + (size_t)(n0 + rloc) * D + c * 8;
        int aoff[2], boff[2];
        #pragma unroll
        for (int mt = 0; mt < 2; mt++) aoff[mt] = swz_frag(wm + mt * 16 + l16, quad);
        #pragma unroll
        for (int nt = 0; nt < 2; nt++) boff[nt] = swz_frag(wn + nt * 16 + l16, quad);
        int wrA = w * 512 + l * 8;
        f32x4 acc[2][2] = {};
        for (int kk = 0; kk < D; kk += 32) {
            short8 ha, la, hb, lb;
            split8(pax + kk, ha, la);
            split8(pbw + kk, hb, lb);
            *(short8*)(sAh + wrA) = ha;
            *(short8*)(sAl + wrA) = la;
            *(short8*)(sBh + wrA) = hb;
            *(short8*)(sBl + wrA) = lb;
            __syncthreads();
            short8 ah[2], al[2], bh[2], bl[2];
            #pragma unroll
            for (int mt = 0; mt < 2; mt++) {
                ah[mt] = *(const short8*)(sAh + aoff[mt]);
                al[mt] = *(const short8*)(sAl + aoff[mt]);
            }
            #pragma unroll
            for (int nt = 0; nt < 2; nt++) {
                bh[nt] = *(const short8*)(sBh + boff[nt]);
                bl[nt] = *(const short8*)(sBl + boff[nt]);
            }
            #pragma unroll
            for (int mt = 0; mt < 2; mt++)
                #pragma unroll
                for (int nt = 0; nt < 2; nt++) {
                    acc[mt][nt] = __builtin_amdgcn_mfma_f32_16x16x32_bf16(ah[mt], bh[nt], acc[mt][nt], 0, 0, 0);
                    acc[mt][nt] = __builtin_amdgcn_mfma_f32_16x16x32_bf16(ah[mt], bl[nt], acc[mt][nt], 0, 0, 0);
                    acc[mt][nt] = __builtin_amdgcn_mfma_f32_16x16x32_bf16(al[mt], bh[nt], acc[mt][nt], 0, 0, 0);
                }
            __syncthreads();
        }
        #pragma unroll
        for (int mt = 0; mt < 2; mt++)
            #pragma unroll
            for (int nt = 0; nt < 2; nt++) {
                int n = n0 + wn + nt * 16 + l16;
                float bv = b1[n];
                #pragma unroll
                for (int r = 0; r < 4; r++) {
                    int m = m0 + wm + mt * 16 + quad * 4 + r;
                    float z = acc[mt][nt][r] + bv;
                    size_t idx = (size_t)m * D1 + n;
                    dists[idx] = fabsf(z);          // rn1 division deferred to topk
                    m1q[idx] = (z > 0.f) ? 0xFFu : 0u;
                    float h = z > 0.f ? z : 0.f;
                    unsigned short hh = f2bf(h);
                    h1hi[idx] = hh;
                    h1lo[idx] = f2bf(h - bf2f(hh));
                }
            }
        return;
    }
    if (blk < 448) {                                   // zero region (float4)
        if (blk == 64 && t == 0) outp[0] = 0.f;
        int i4 = (blk - 64) * 1024 + t * 4;
        *(float4*)(zeros + i4) = make_float4(0.f, 0.f, 0.f, 0.f);
        return;
    }
    if (blk < 480) {                                   // W1 col quant -> W1Ti8
        int ty = t >> 5, tx = t & 31;
        int d = (blk - 448) * 8 + ty;
        float m = 0.f;
        for (int i = tx; i < D1; i += 32) m = fmaxf(m, fabsf(W1[(size_t)i * D + d]));
        #pragma unroll
        for (int off = 16; off > 0; off >>= 1) m = fmaxf(m, __shfl_down(m, off, 32));
        m = __shfl(m, 0, 32);
        m = fmaxf(m, 1e-20f);
        if (tx == 0) saq[d] = m / 127.f;
        float inv = 127.f / m;
        for (int i = tx; i < D1; i += 32) {
            int q = __float2int_rn(W1[(size_t)i * D + d] * inv);
            W1Ti8[(size_t)d * D1 + i] = (signed char)q;
        }
        return;
    }
    if (blk < 608) {                     // W2 row quant + bf16 split (fused)
        int o = (blk - 480) * 4 + (t >> 6);
        int l = t & 63;
        const float* row = W2 + (size_t)o * D1;
        float4 v[4];
        #pragma unroll
        for (int jj = 0; jj < 4; jj++) v[jj] = *(const float4*)(row + jj * 256 + l * 4);
        float m = 0.f;
        #pragma unroll
        for (int jj = 0; jj < 4; jj++)
            m = fmaxf(m, fmaxf(fmaxf(fabsf(v[jj].x), fabsf(v[jj].y)),
                               fmaxf(fabsf(v[jj].z), fabsf(v[jj].w))));
        m = waveReduceMax(m);
        m = __shfl(m, 0, 64);
        m = fmaxf(m, 1e-20f);
        if (l == 0) sbq[o] = m / 127.f;
        float inv = 127.f / m;
        #pragma unroll
        for (int jj = 0; jj < 4; jj++) {
            int base = jj * 256 + l * 4;
            int q0 = __float2int_rn(v[jj].x * inv);
            int q1 = __float2int_rn(v[jj].y * inv);
            int q2 = __float2int_rn(v[jj].z * inv);
            int q3 = __float2int_rn(v[jj].w * inv);
            unsigned int pk = (unsigned)(q0 & 255) | ((unsigned)(q1 & 255) << 8) |
                              ((unsigned)(q2 & 255) << 16) | ((unsigned)(q3 & 255) << 24);
            *(unsigned int*)(W2i8 + (size_t)o * D1 + base) = pk;
            ushort4 h, lo;
            h.x = f2bf(v[jj].x); lo.x = f2bf(v[jj].x - bf2f(h.x));
            h.y = f2bf(v[jj].y); lo.y = f2bf(v[jj].y - bf2f(h.y));
            h.z = f2bf(v[jj].z); lo.z = f2bf(v[jj].z - bf2f(h.z));
            h.w = f2bf(v[jj].w); lo.w = f2bf(v[jj].w - bf2f(h.w));
            *(ushort4*)(W2hi + (size_t)o * D1 + base) = h;
            *(ushort4*)(W2lo + (size_t)o * D1 + base) = lo;
        }
        return;
    }
    if (blk < 672) {                     // W3 row quant + bf16 split (fused)
        int p = (blk - 608) * 4 + (t >> 6);
        int l = t & 63;
        const float* row = W3 + (size_t)p * D2;
        float4 v[2];
        #pragma unroll
        for (int jj = 0; jj < 2; jj++) v[jj] = *(const float4*)(row + jj * 256 + l * 4);
        float m = 0.f;
        #pragma unroll
        for (int jj = 0; jj < 2; jj++)
            m = fmaxf(m, fmaxf(fmaxf(fabsf(v[jj].x), fabsf(v[jj].y)),
                               fmaxf(fabsf(v[jj].z), fabsf(v[jj].w))));
        m = waveReduceMax(m);
        m = __shfl(m, 0, 64);
        m = fmaxf(m, 1e-20f);
        if (l == 0) s3q[p] = m / 127.f;
        float inv = 127.f / m;
        #pragma unroll
        for (int jj = 0; jj < 2; jj++) {
            int base = jj * 256 + l * 4;
            int q0 = __float2int_rn(v[jj].x * inv);
            int q1 = __float2int_rn(v[jj].y * inv);
            int q2 = __float2int_rn(v[jj].z * inv);
            int q3 = __float2int_rn(v[jj].w * inv);
            unsigned int pk = (unsigned)(q0 & 255) | ((unsigned)(q1 & 255) << 8) |
                              ((unsigned)(q2 & 255) << 16) | ((unsigned)(q3 & 255) << 24);
            *(unsigned int*)(W3i8 + (size_t)p * D2 + base) = pk;
            ushort4 h, lo;
            h.x = f2bf(v[jj].x); lo.x = f2bf(v[jj].x - bf2f(h.x));
            h.y = f2bf(v[jj].y); lo.y = f2bf(v[jj].y - bf2f(h.y));
            h.z = f2bf(v[jj].z); lo.z = f2bf(v[jj].z - bf2f(h.z));
            h.w = f2bf(v[jj].w); lo.w = f2bf(v[jj].w - bf2f(h.w));
            *(ushort4*)(W3hi + (size_t)p * D2 + base) = h;
            *(ushort4*)(W3lo + (size_t)p * D2 + base) = lo;
        }
        return;
    }
    {                                                  // rn1 (256 blks, topk-only)
        int gw = (blk - 672) * 4 + (t >> 6);
        int lane = t & 63;
        const float* row = W1 + (size_t)gw * D;
        float s = 0.f;
        for (int tt = lane; tt < D; tt += 64) { float v = row[tt]; s += v * v; }
        s = waveReduceSum(s);
        if (lane == 0) rn1[gw] = sqrtf(s);
    }
}

// ---- merged dispatch 2: l2a (blocks 0..127) || gemm1 (128..1151) -----------
// gemm1: 128d x 64o, G=4 + counted-vmcnt dbuf, A-side mask (session best:
// ~45us k_big1, ~159us total). FROZEN — final configuration.
__global__ __launch_bounds__(256, 2) void k_big1(
    const unsigned short* __restrict__ h1hi, const unsigned short* __restrict__ h1lo,
    const unsigned short* __restrict__ W2hi, const unsigned short* __restrict__ W2lo,
    float* __restrict__ z2,
    const signed char* __restrict__ W1Ti8,   // [256][1024]  A rows (d)
    const signed char* __restrict__ W2i8,    // [512][1024]  B rows (o)
    const unsigned char* __restrict__ m1q,   // [B][1024]
    const float* __restrict__ saq,           // [256]
    const float* __restrict__ sbq,           // [512]
    signed char* __restrict__ qV2,           // [256][256][512] (d-major)
    float* __restrict__ norm2) {             // [B][512]
    __shared__ __align__(16) unsigned char smem[53248]; // 2x24K dbuf + 4K masks
    int bid = blockIdx.x;

    if (bid < 128) {
        // ---- l2a: split-K partial z2 (atomic; bias folded downstream) ----
        unsigned short* sm = (unsigned short*)smem;
        int m0 = (bid & 3) * 64, n0 = ((bid >> 2) & 7) * 64, k0 = (bid >> 5) * 256;
        f32x4 acc[2][2] = {};
        mfma3_64<D1, 256>(h1hi, h1lo, W2hi, W2lo, m0, n0, k0, sm, acc);
        int l = threadIdx.x & 63, w = threadIdx.x >> 6;
        int quad = l >> 4, l16 = l & 15;
        int wm = (w >> 1) * 32, wn = (w & 1) * 32;
        #pragma unroll
        for (int mt = 0; mt < 2; mt++)
            #pragma unroll
            for (int nt = 0; nt < 2; nt++) {
                int n = n0 + wn + nt * 16 + l16;
                #pragma unroll
                for (int r = 0; r < 4; r++) {
                    int m = m0 + wm + mt * 16 + quad * 4 + r;
                    atomicAdd(&z2[(size_t)m * D2 + n], acc[mt][nt][r]);
                }
            }
        return;
    }

    // ---- gemm1 (i8, BK=128, 128d x 64o, G=4; counted-vmcnt dbuf) ----
    int j = bid - 128;                 // 0..1023
    unsigned char* mbuf = (unsigned char*)smem + 49152;  // [4][1024] masks
    int m0 = (j & 1) * 128;           // d tile
    int o0 = ((j >> 1) & 7) * 64;     // o tile
    int b0 = (j >> 4) * 4;            // first batch of quad
    int tid = threadIdx.x;
    int l = tid & 63, w = tid >> 6;
    int quad = l >> 4, l16 = l & 15;
    int wm = (w >> 1) * 64, wn = (w & 1) * 32;

    // stage 4 batches' mask rows (4 KB over 256 threads, 16 B each)
    *(int4*)(mbuf + tid * 16) = *(const int4*)(m1q + (size_t)b0 * D1 + tid * 16);

    const signed char* pa[4];
    const signed char* pb[2];
    int lrow = l >> 3, ls = l & 7;
    #pragma unroll
    for (int r = 0; r < 4; r++) {
        int row = r * 32 + w * 8 + lrow;
        int c = (ls + (row & 7)) & 7;
        pa[r] = W1Ti8 + (size_t)(m0 + row) * D1 + c * 16;
    }
    #pragma unroll
    for (int r = 0; r < 2; r++) {
        int row = r * 32 + w * 8 + lrow;
        int c = (ls + (row & 7)) & 7;
        pb[r] = W2i8 + (size_t)(o0 + row) * D1 + c * 16;
    }
    int aoff[4][2], boff[2][2];
    #pragma unroll
    for (int mt = 0; mt < 4; mt++) {
        int tr = wm + mt * 16 + l16;
        #pragma unroll
        for (int ks = 0; ks < 2; ks++)
            aoff[mt][ks] = tr * 128 + (((ks * 4 + quad) - (tr & 7)) & 7) * 16;
    }
    #pragma unroll
    for (int nt = 0; nt < 2; nt++) {
        int tr = wn + nt * 16 + l16;
        #pragma unroll
        for (int ks = 0; ks < 2; ks++)
            boff[nt][ks] = tr * 128 + (((ks * 4 + quad) - (tr & 7)) & 7) * 16;
    }

    i32x4 acc[4][4][2];
    #pragma unroll
    for (int g = 0; g < 4; g++)
        #pragma unroll
        for (int i = 0; i < 4; i++)
            #pragma unroll
            for (int jj = 0; jj < 2; jj++) acc[g][i][jj] = (i32x4)0;

    // prologue: tile 0 -> buf0; masks staged; one full drain
    {
        signed char* buf0 = (signed char*)smem;
        #pragma unroll
        for (int r = 0; r < 4; r++)
            gld16(pa[r], buf0 + r * 4096 + w * 1024);
        #pragma unroll
        for (int r = 0; r < 2; r++)
            gld16(pb[r], buf0 + 16384 + r * 4096 + w * 1024);
    }
    __syncthreads();

    for (int t = 0; t < 8; t++) {
        const signed char* bufc = (const signed char*)smem + (t & 1) * 24576;
        signed char* bufn = (signed char*)smem + ((t + 1) & 1) * 24576;
        if (t < 7) {
            int kn = (t + 1) * 128;
            #pragma unroll
            for (int r = 0; r < 4; r++)
                gld16(pa[r] + kn, bufn + r * 4096 + w * 1024);
            #pragma unroll
            for (int r = 0; r < 2; r++)
                gld16(pb[r] + kn, bufn + 16384 + r * 4096 + w * 1024);
            asm volatile("s_waitcnt vmcnt(6)" ::: "memory");
        } else {
            asm volatile("s_waitcnt vmcnt(0)" ::: "memory");
        }
        __builtin_amdgcn_s_barrier();       // all waves' tile-t loads landed
        __builtin_amdgcn_sched_barrier(0);  // pin: no ds_read hoisted above
        const signed char* As = bufc;
        const signed char* Bs = bufc + 16384;
        #pragma unroll
        for (int ks = 0; ks < 2; ks++) {
            i32x4 mv[4];
            #pragma unroll
            for (int g = 0; g < 4; g++)
                mv[g] = *(const i32x4*)(mbuf + g * 1024 + t * 128 + ks * 64 + quad * 16);
            i32x4 a[4], bq[2];
            #pragma unroll
            for (int mt = 0; mt < 4; mt++)
                a[mt] = *(const i32x4*)(As + aoff[mt][ks]);
            #pragma unroll
            for (int nt = 0; nt < 2; nt++)
                bq[nt] = *(const i32x4*)(Bs + boff[nt][ks]);
            #pragma unroll
            for (int g = 0; g < 4; g++) {
                #pragma unroll
                for (int mt = 0; mt < 4; mt++) {
                    i32x4 ag = a[mt] & mv[g];
                    #pragma unroll
                    for (int nt = 0; nt < 2; nt++)
                        acc[g][mt][nt] = __builtin_amdgcn_mfma_i32_16x16x64_i8(
                            ag, bq[nt], acc[g][mt][nt], 0, 0, 0);
                }
            }
        }
        // all reads of bufc complete (in regs) before any wave issues the
        // iter t+1 DMA writes that target this buffer
        __builtin_amdgcn_s_barrier();
    }

    // ---- fused epilogue per batch: single-pass cvt, sbv^2 factored out ----
    float sad[4][4];
    #pragma unroll
    for (int mt = 0; mt < 4; mt++)
        #pragma unroll
        for (int r = 0; r < 4; r++)
            sad[mt][r] = saq[m0 + wm + mt * 16 + quad * 4 + r];
    float sbv[2], sbdq[2];
    #pragma unroll
    for (int nt = 0; nt < 2; nt++) {
        sbv[nt] = sbq[o0 + wn + nt * 16 + l16];
        sbdq[nt] = sbv[nt] * (1.0f / CQ);
    }

    #pragma unroll
    for (int g = 0; g < 4; g++) {
        int bg = b0 + g;
        float nrm[2] = {0.f, 0.f};
        signed char* qb = qV2 + (size_t)bg * (D * D2);
        #pragma unroll
        for (int mt = 0; mt < 4; mt++) {
            int dbase = m0 + wm + mt * 16 + quad * 4;
            #pragma unroll
            for (int r = 0; r < 4; r++) {
                float sa = sad[mt][r];
                size_t rowoff = (size_t)(dbase + r) * D2;
                #pragma unroll
                for (int nt = 0; nt < 2; nt++) {
                    float tv = (float)acc[g][mt][nt][r];
                    float u = tv * sa;
                    nrm[nt] = fmaf(u, u, nrm[nt]);
                    int qi = __float2int_rn(tv * sbdq[nt]);
                    qi = max(-127, min(127, qi));
                    qb[rowoff + o0 + wn + nt * 16 + l16] = (signed char)qi;
                }
            }
        }
        #pragma unroll
        for (int nt = 0; nt < 2; nt++) {
            float s = nrm[nt] * (sbv[nt] * sbv[nt]);
            s += __shfl_down(s, 32, 64);
            s += __shfl_down(s, 16, 64);
            if (l < 16)
                atomicAdd(&norm2[(size_t)bg * D2 + o0 + wn + nt * 16 + l], s);
        }
    }
}

// ---- merged dispatch 3: l3a z2-direct (0..31) || gemm2 (32..1055) ----------
// (R5 exact: single-buffer 33 KB — proven best; frozen)
__global__ __launch_bounds__(256) void k_big2(
    const float* __restrict__ z2,            // [B][512] (bias NOT applied)
    const float* __restrict__ b2,            // [512]
    const unsigned short* __restrict__ W3hi, const unsigned short* __restrict__ W3lo,
    float* __restrict__ z3,
    const signed char* __restrict__ W3i8,    // [256][512]
    const signed char* __restrict__ qV2,     // [256][256][512]
    const float* __restrict__ saq,           // [256]
    const float* __restrict__ s3q,           // [256]
    float* __restrict__ norm3) {             // [B][256]
    __shared__ __align__(16) unsigned char smem[33280];  // 32K tiles + 512B mask
    int bid = blockIdx.x;
    int tid = threadIdx.x;

    if (bid < 32) {
        // ---- l3a: split-K partial z3; A = relu(z2+b2) hi/lo computed inline
        unsigned short* sAh = (unsigned short*)smem;
        unsigned short* sAl = sAh + 2048;
        unsigned short* sBh = sAh + 4096;
        unsigned short* sBl = sAh + 6144;
        int m0 = (bid & 3) * 64, n0 = ((bid >> 2) & 3) * 64, k0 = (bid >> 4) * 256;
        int l = tid & 63, w = tid >> 6;
        int rsub = l >> 2;
        int quad = l >> 4, l16 = l & 15;
        int wm = (w >> 1) * 32, wn = (w & 1) * 32;
        int rloc = w * 16 + rsub;
        int c = swz_src(rloc, l);
        const float* pz  = z2 + (size_t)(m0 + rloc) * D2 + k0 + c * 8;
        const float* pbi = b2 + k0 + c * 8;
        const unsigned short* pb = W3hi + (size_t)(n0 + rloc) * D2 + k0 + c * 8;
        ptrdiff_t dB = W3lo - W3hi;
        int aoff[2], boff[2];
        #pragma unroll
        for (int mt = 0; mt < 2; mt++) aoff[mt] = swz_frag(wm + mt * 16 + l16, quad);
        #pragma unroll
        for (int nt = 0; nt < 2; nt++) boff[nt] = swz_frag(wn + nt * 16 + l16, quad);
        int wrA = w * 512 + l * 8;
        f32x4 acc[2][2] = {};
        for (int kk = 0; kk < 256; kk += 32) {
            gld16(pb + kk,      sBh + w * 512);
            gld16(pb + dB + kk, sBl + w * 512);
            float4 za = *(const float4*)(pz + kk);
            float4 zb = *(const float4*)(pz + kk + 4);
            float4 ba = *(const float4*)(pbi + kk);
            float4 bb = *(const float4*)(pbi + kk + 4);
            float hv[8] = { za.x + ba.x, za.y + ba.y, za.z + ba.z, za.w + ba.w,
                            zb.x + bb.x, zb.y + bb.y, zb.z + bb.z, zb.w + bb.w };
            short8 h8, l8;
            #pragma unroll
            for (int q2 = 0; q2 < 8; q2++) {
                float h = hv[q2] > 0.f ? hv[q2] : 0.f;
                unsigned short hh = f2bf(h);
                h8[q2] = (short)hh;
                l8[q2] = (short)f2bf(h - bf2f(hh));
            }
            *(short8*)(sAh + wrA) = h8;
            *(short8*)(sAl + wrA) = l8;
            __syncthreads();
            short8 ah[2], al[2], bh[2], bl[2];
            #pragma unroll
            for (int mt = 0; mt < 2; mt++) {
                ah[mt] = *(const short8*)(sAh + aoff[mt]);
                al[mt] = *(const short8*)(sAl + aoff[mt]);
            }
            #pragma unroll
            for (int nt = 0; nt < 2; nt++) {
                bh[nt] = *(const short8*)(sBh + boff[nt]);
                bl[nt] = *(const short8*)(sBl + boff[nt]);
            }
            #pragma unroll
            for (int mt = 0; mt < 2; mt++)
                #pragma unroll
                for (int nt = 0; nt < 2; nt++) {
                    acc[mt][nt] = __builtin_amdgcn_mfma_f32_16x16x32_bf16(ah[mt], bh[nt], acc[mt][nt], 0, 0, 0);
                    acc[mt][nt] = __builtin_amdgcn_mfma_f32_16x16x32_bf16(ah[mt], bl[nt], acc[mt][nt], 0, 0, 0);
                    acc[mt][nt] = __builtin_amdgcn_mfma_f32_16x16x32_bf16(al[mt], bh[nt], acc[mt][nt], 0, 0, 0);
                }
            __syncthreads();
        }
        #pragma unroll
        for (int mt = 0; mt < 2; mt++)
            #pragma unroll
            for (int nt = 0; nt < 2; nt++) {
                int n = n0 + wn + nt * 16 + l16;
                #pragma unroll
                for (int r = 0; r < 4; r++) {
                    int m = m0 + wm + mt * 16 + quad * 4 + r;
                    atomicAdd(&z3[(size_t)m * D3 + n], acc[mt][nt][r]);
                }
            }
        return;
    }

    // ---- gemm2 (i8, BK=128): norm3; m2 mask from z2+b2 in LDS ----
    int j = bid - 32;
    signed char* As = (signed char*)smem;
    signed char* Bs = (signed char*)smem + 16384;
    unsigned char* mbuf = (unsigned char*)smem + 32768;  // 512 B
    int m0 = (j & 1) * 128;           // p
    int n0 = ((j >> 1) & 1) * 128;    // d
    int bc = j >> 2;                  // batch
    int l = tid & 63, w = tid >> 6;
    int quad = l >> 4, l16 = l & 15;
    int wm = (w >> 1) * 64, wn = (w & 1) * 64;
    const signed char* Bsrc = qV2 + (size_t)bc * (D * D2);

    {   // fill m2 mask row for this batch
        #pragma unroll
        for (int rr = 0; rr < 2; rr++) {
            int o = tid * 2 + rr;
            float z = z2[(size_t)bc * D2 + o] + b2[o];
            mbuf[o] = (z > 0.f) ? 0xFFu : 0u;
        }
    }
    __syncthreads();

    const signed char* pa[4];
    const signed char* pb[4];
    int lrow = l >> 3, ls = l & 7;
    #pragma unroll
    for (int r = 0; r < 4; r++) {
        int row = r * 32 + w * 8 + lrow;
        int c = (ls + (row & 7)) & 7;
        pa[r] = W3i8 + (size_t)(m0 + row) * D2 + c * 16;
        pb[r] = Bsrc + (size_t)(n0 + row) * D2 + c * 16;
    }
    int aoff[4][2], boff[4][2];
    #pragma unroll
    for (int mt = 0; mt < 4; mt++) {
        int tr = wm + mt * 16 + l16;
        #pragma unroll
        for (int ks = 0; ks < 2; ks++)
            aoff[mt][ks] = tr * 128 + (((ks * 4 + quad) - (tr & 7)) & 7) * 16;
    }
    #pragma unroll
    for (int nt = 0; nt < 4; nt++) {
        int tr = wn + nt * 16 + l16;
        #pragma unroll
        for (int ks = 0; ks < 2; ks++)
            boff[nt][ks] = tr * 128 + (((ks * 4 + quad) - (tr & 7)) & 7) * 16;
    }

    i32x4 acc[4][4];
    #pragma unroll
    for (int i = 0; i < 4; i++)
        #pragma unroll
        for (int jj = 0; jj < 4; jj++) acc[i][jj] = (i32x4)0;

    for (int kk = 0; kk < D2; kk += 128) {
        #pragma unroll
        for (int r = 0; r < 4; r++) {
            gld16(pa[r] + kk, As + r * 4096 + w * 1024);
            gld16(pb[r] + kk, Bs + r * 4096 + w * 1024);
        }
        __syncthreads();
        i32x4 mv0 = *(const i32x4*)(mbuf + kk + quad * 16);
        i32x4 mv1 = *(const i32x4*)(mbuf + kk + 64 + quad * 16);
        #pragma unroll
        for (int ks = 0; ks < 2; ks++) {
            i32x4 mv = ks ? mv1 : mv0;
            i32x4 a[4], bq[4];
            #pragma unroll
            for (int mt = 0; mt < 4; mt++)
                a[mt] = *(const i32x4*)(As + aoff[mt][ks]);
            #pragma unroll
            for (int nt = 0; nt < 4; nt++)
                bq[nt] = (*(const i32x4*)(Bs + boff[nt][ks])) & mv;
            #pragma unroll
            for (int mt = 0; mt < 4; mt++)
                #pragma unroll
                for (int nt = 0; nt < 4; nt++)
                    acc[mt][nt] = __builtin_amdgcn_mfma_i32_16x16x64_i8(
                        a[mt], bq[nt], acc[mt][nt], 0, 0, 0);
        }
        __syncthreads();
    }

    float saCQ[4];
    #pragma unroll
    for (int nt = 0; nt < 4; nt++)
        saCQ[nt] = saq[n0 + wn + nt * 16 + l16] * CQ;

    #pragma unroll
    for (int mt = 0; mt < 4; mt++)
        #pragma unroll
        for (int r = 0; r < 4; r++) {
            float s = 0.f;
            #pragma unroll
            for (int nt = 0; nt < 4; nt++) {
                float v = (float)acc[mt][nt][r] * saCQ[nt];
                s += v * v;
            }
            s += __shfl_down(s, 8, 64);
            s += __shfl_down(s, 4, 64);
            s += __shfl_down(s, 2, 64);
            s += __shfl_down(s, 1, 64);
            if (l16 == 0) {
                int p = m0 + wm + mt * 16 + quad * 4 + r;
                float s3 = s3q[p];
                atomicAdd(&norm3[(size_t)bc * D3 + p], s * s3 * s3);
            }
        }
}

// ---- wave-per-batch k-smallest sum (dist1 = |z1|/rn1 computed inline) ------
__global__ __launch_bounds__(256) void k_topk(
    const float* __restrict__ dists,    // [B][D1] |z1| only
    const float* __restrict__ rn1,      // [D1]
    const float* __restrict__ z2, const float* __restrict__ b2,
    const float* __restrict__ norm2,
    const float* __restrict__ z3, const float* __restrict__ b3,
    const float* __restrict__ norm3,
    const int* __restrict__ kp, float* __restrict__ outp) {
    int t = threadIdx.x;
    int wv = t >> 6, lane = t & 63;
    int b = blockIdx.x * 4 + wv;
    float lv[28];
    #pragma unroll
    for (int j = 0; j < 16; j++) {
        int n = lane + 64 * j;
        lv[j] = dists[(size_t)b * D1 + n] / rn1[n];
    }
    #pragma unroll
    for (int j = 16; j < 24; j++) {
        int o = lane + 64 * (j - 16);
        float zz = z2[(size_t)b * D2 + o] + b2[o];
        lv[j] = fabsf(zz) / sqrtf(norm2[(size_t)b * D2 + o]);
    }
    #pragma unroll
    for (int j = 24; j < 28; j++) {
        int p = lane + 64 * (j - 24);
        float zz = z3[(size_t)b * D3 + p] + b3[p];
        lv[j] = fabsf(zz) / sqrtf(norm3[(size_t)b * D3 + p]);
    }
    int k = *kp;
    if (k > NDIST) k = NDIST;
    float sum = 0.f;
    for (int it = 0; it < k; it++) {
        float mv = lv[0]; int mj = 0;
        #pragma unroll
        for (int j = 1; j < 28; j++)
            if (lv[j] < mv) { mv = lv[j]; mj = j; }
        unsigned long long key =
            ((unsigned long long)__float_as_uint(mv) << 32) | (unsigned)(lane * 32 + mj);
        #pragma unroll
        for (int off = 1; off < 64; off <<= 1) {
            unsigned long long o = __shfl_xor(key, off, 64);
            if (o < key) key = o;
        }
        sum += __uint_as_float((unsigned)(key >> 32));
        int wl = (int)((key >> 5) & 63u), wj = (int)(key & 31u);
        if (lane == wl) lv[wj] = FLT_MAX;
    }
    if (lane == 0) atomicAdd(outp, sum);
}

extern "C" void kernel_launch(void* const* d_in, const int* in_sizes, int n_in,
                              void* d_out, int out_size, void* d_ws, size_t ws_size,
                              hipStream_t stream) {
    const float* x  = (const float*)d_in[0];
    const float* W1 = (const float*)d_in[1];
    const float* b1 = (const float*)d_in[2];
    const float* W2 = (const float*)d_in[3];
    const float* b2 = (const float*)d_in[4];
    const float* W3 = (const float*)d_in[5];
    const float* b3 = (const float*)d_in[6];
    const int*   kp = (const int*)d_in[7];
    float* outp = (float*)d_out;

    float* fp = (float*)d_ws;
    float* rn1     = fp;                          fp += D1;
    float* dists   = fp;                          fp += (size_t)B * D1;
    float* saq     = fp;                          fp += D;
    float* sbq     = fp;                          fp += D2;
    float* s3q     = fp;                          fp += D3;
    // zero region: z2 || z3 || norm2 || norm3 (contiguous, 393216 floats)
    float* z2      = fp;                          fp += (size_t)B * D2;
    float* z3      = fp;                          fp += (size_t)B * D3;
    float* norm2   = fp;                          fp += (size_t)B * D2;
    float* norm3   = fp;                          fp += (size_t)B * D3;
    unsigned short* up = (unsigned short*)fp;
    unsigned short* W2hi  = up;  up += (size_t)D2 * D1;
    unsigned short* W2lo  = up;  up += (size_t)D2 * D1;
    unsigned short* W3hi  = up;  up += (size_t)D3 * D2;
    unsigned short* W3lo  = up;  up += (size_t)D3 * D2;
    unsigned short* h1hi  = up;  up += (size_t)B * D1;
    unsigned short* h1lo  = up;  up += (size_t)B * D1;
    signed char*    cp = (signed char*)up;
    signed char*    W1Ti8 = cp;  cp += (size_t)D * D1;
    signed char*    W2i8  = cp;  cp += (size_t)D2 * D1;
    signed char*    W3i8  = cp;  cp += (size_t)D3 * D2;
    unsigned char*  m1q   = (unsigned char*)cp;  cp += (size_t)B * D1;
    signed char*    qV2   = cp;   // full 256-batch (33.5 MB; ws proven since R10)

    // l1 gemm (64) + zeros (384) + W1 quant (32) + fused W2 quant+split (128)
    // + fused W3 quant+split (64) + rn1 (256) = 928 blocks
    k_l1p<<<928, 256, 0, stream>>>(x, W1, W2, W3, b1,
                                   dists, m1q, h1hi, h1lo,
                                   z2, outp, W2hi, W2lo, W3hi, W3lo,
                                   W1Ti8, saq, W2i8, sbq, W3i8, s3q, rn1);

    // l2a (128) || gemm1 (1024, 128d x 64o, G=4, counted-vmcnt dbuf, A-mask)
    k_big1<<<1152, 256, 0, stream>>>(h1hi, h1lo, W2hi, W2lo, z2,
                                     W1Ti8, W2i8, m1q, saq, sbq, qV2, norm2);

    // l3a z2-direct (32) || gemm2 single-buffer (R5 exact)
    k_big2<<<1056, 256, 0, stream>>>(z2, b2, W3hi, W3lo, z3,
                                     W3i8, qV2, saq, s3q, norm3);

    k_topk<<<B / 4, 256, 0, stream>>>(dists, rn1, z2, b2, norm2, z3, b3, norm3,
                                      kp, outp);
}

// Round 23
// 160.400 us; speedup vs baseline: 1.0061x; 1.0061x over previous
//
#include <hip/hip_runtime.h>
#include <math.h>
#include <float.h>

#define B   256
#define D   256
#define D1  1024
#define D2  512
#define D3  256
#define NDIST (D1 + D2 + D3)   // 1792
#define CQ  2.0f               // qV2 static scale multiplier (step = sa[d]*CQ)

typedef __attribute__((ext_vector_type(8))) short short8;
typedef __attribute__((ext_vector_type(4))) float f32x4;
typedef __attribute__((ext_vector_type(4))) int   i32x4;

__device__ __forceinline__ float waveReduceSum(float v) {
    #pragma unroll
    for (int off = 32; off > 0; off >>= 1)
        v += __shfl_down(v, off, 64);
    return v;
}
__device__ __forceinline__ float waveReduceMax(float v) {
    #pragma unroll
    for (int off = 32; off > 0; off >>= 1)
        v = fmaxf(v, __shfl_down(v, off, 64));
    return v;
}
__device__ __forceinline__ unsigned short f2bf(float f) {
    unsigned int u = __float_as_uint(f);
    u = (u + 0x7FFFu + ((u >> 16) & 1u)) >> 16;   // RNE
    return (unsigned short)u;
}
__device__ __forceinline__ float bf2f(unsigned short h) {
    return __uint_as_float(((unsigned int)h) << 16);
}
__device__ __forceinline__ void gld16(const void* g, void* l) {
    __builtin_amdgcn_global_load_lds(
        (const __attribute__((address_space(1))) unsigned int*)g,
        (__attribute__((address_space(3))) unsigned int*)l, 16, 0, 0);
}
__device__ __forceinline__ int swz_src(int row, int lane) {
    return ((lane & 3) + ((row >> 1) & 3)) & 3;
}
__device__ __forceinline__ int swz_frag(int row, int quad) {
    return row * 32 + (((quad - ((row >> 1) & 3)) & 3) * 8);
}

// load 8 fp32, split to bf16 hi/lo short8
__device__ __forceinline__ void split8(const float* p, short8& h8, short8& l8) {
    float4 a = *(const float4*)(p);
    float4 b = *(const float4*)(p + 4);
    float hv[8] = { a.x, a.y, a.z, a.w, b.x, b.y, b.z, b.w };
    #pragma unroll
    for (int q = 0; q < 8; q++) {
        unsigned short hh = f2bf(hv[q]);
        h8[q] = (short)hh;
        l8[q] = (short)f2bf(hv[q] - bf2f(hh));
    }
}

// ---- compensated bf16 MFMA mainloop, 64x64 tile, K range [k0, k0+KL) -------
template <int KD, int KL>
__device__ __forceinline__ void mfma3_64(
    const unsigned short* __restrict__ Ahi, const unsigned short* __restrict__ Alo,
    const unsigned short* __restrict__ Bhi, const unsigned short* __restrict__ Blo,
    int m0, int n0, int k0, unsigned short* sm, f32x4 acc[2][2]) {
    int tid = threadIdx.x;
    int l = tid & 63, w = tid >> 6;
    int rsub = l >> 2;
    int quad = l >> 4, l16 = l & 15;
    int wm = (w >> 1) * 32, wn = (w & 1) * 32;
    unsigned short* sAh = sm;
    unsigned short* sAl = sm + 2048;
    unsigned short* sBh = sm + 4096;
    unsigned short* sBl = sm + 6144;
    ptrdiff_t dA = Alo - Ahi, dB = Blo - Bhi;
    int rloc = w * 16 + rsub;
    int c = swz_src(rloc, l);
    const unsigned short* pa = Ahi + (size_t)(m0 + rloc) * KD + k0 + c * 8;
    const unsigned short* pb = Bhi + (size_t)(n0 + rloc) * KD + k0 + c * 8;
    int aoff[2], boff[2];
    #pragma unroll
    for (int mt = 0; mt < 2; mt++) aoff[mt] = swz_frag(wm + mt * 16 + l16, quad);
    #pragma unroll
    for (int nt = 0; nt < 2; nt++) boff[nt] = swz_frag(wn + nt * 16 + l16, quad);
    for (int kk = 0; kk < KL; kk += 32) {
        gld16(pa + kk,      sAh + w * 512);
        gld16(pa + dA + kk, sAl + w * 512);
        gld16(pb + kk,      sBh + w * 512);
        gld16(pb + dB + kk, sBl + w * 512);
        __syncthreads();
        short8 ah[2], al[2], bh[2], bl[2];
        #pragma unroll
        for (int mt = 0; mt < 2; mt++) {
            ah[mt] = *(const short8*)(sAh + aoff[mt]);
            al[mt] = *(const short8*)(sAl + aoff[mt]);
        }
        #pragma unroll
        for (int nt = 0; nt < 2; nt++) {
            bh[nt] = *(const short8*)(sBh + boff[nt]);
            bl[nt] = *(const short8*)(sBl + boff[nt]);
        }
        #pragma unroll
        for (int mt = 0; mt < 2; mt++)
            #pragma unroll
            for (int nt = 0; nt < 2; nt++) {
                acc[mt][nt] = __builtin_amdgcn_mfma_f32_16x16x32_bf16(ah[mt], bh[nt], acc[mt][nt], 0, 0, 0);
                acc[mt][nt] = __builtin_amdgcn_mfma_f32_16x16x32_bf16(ah[mt], bl[nt], acc[mt][nt], 0, 0, 0);
                acc[mt][nt] = __builtin_amdgcn_mfma_f32_16x16x32_bf16(al[mt], bh[nt], acc[mt][nt], 0, 0, 0);
            }
        __syncthreads();
    }
}

// ---- dispatch 1: l1 gemm + zeros + fused quant+split jobs + rn1 ------------
__global__ __launch_bounds__(256) void k_l1p(
    const float* __restrict__ x, const float* __restrict__ W1,
    const float* __restrict__ W2, const float* __restrict__ W3,
    const float* __restrict__ b1,
    float* __restrict__ dists, unsigned char* __restrict__ m1q,
    unsigned short* __restrict__ h1hi, unsigned short* __restrict__ h1lo,
    float* __restrict__ zeros, float* __restrict__ outp,
    unsigned short* __restrict__ W2hi, unsigned short* __restrict__ W2lo,
    unsigned short* __restrict__ W3hi, unsigned short* __restrict__ W3lo,
    signed char* __restrict__ W1Ti8, float* __restrict__ saq,
    signed char* __restrict__ W2i8,  float* __restrict__ sbq,
    signed char* __restrict__ W3i8,  float* __restrict__ s3q,
    float* __restrict__ rn1) {
    __shared__ __align__(16) unsigned short sm[8192];
    int blk = blockIdx.x;
    int t = threadIdx.x;

    if (blk < 64) {          // l1: z1 GEMM; A=x, B=W1 staged fp32->hi/lo
        unsigned short* sAh = sm;
        unsigned short* sAl = sm + 2048;
        unsigned short* sBh = sm + 4096;
        unsigned short* sBl = sm + 6144;
        int m0 = (blk & 3) * 64, n0 = (blk >> 2) * 64;
        int l = t & 63, w = t >> 6;
        int rsub = l >> 2;
        int quad = l >> 4, l16 = l & 15;
        int wm = (w >> 1) * 32, wn = (w & 1) * 32;
        int rloc = w * 16 + rsub;
        int c = swz_src(rloc, l);
        const float* pax = x + (size_t)(m0 + rloc) * D + c * 8;
        const float* pbw = W1 + (size_t)(n0 + rloc) * D + c * 8;
        int aoff[2], boff[2];
        #pragma unroll
        for (int mt = 0; mt < 2; mt++) aoff[mt] = swz_frag(wm + mt * 16 + l16, quad);
        #pragma unroll
        for (int nt = 0; nt < 2; nt++) boff[nt] = swz_frag(wn + nt * 16 + l16, quad);
        int wrA = w * 512 + l * 8;
        f32x4 acc[2][2] = {};
        for (int kk = 0; kk < D; kk += 32) {
            short8 ha, la, hb, lb;
            split8(pax + kk, ha, la);
            split8(pbw + kk, hb, lb);
            *(short8*)(sAh + wrA) = ha;
            *(short8*)(sAl + wrA) = la;
            *(short8*)(sBh + wrA) = hb;
            *(short8*)(sBl + wrA) = lb;
            __syncthreads();
            short8 ah[2], al[2], bh[2], bl[2];
            #pragma unroll
            for (int mt = 0; mt < 2; mt++) {
                ah[mt] = *(const short8*)(sAh + aoff[mt]);
                al[mt] = *(const short8*)(sAl + aoff[mt]);
            }
            #pragma unroll
            for (int nt = 0; nt < 2; nt++) {
                bh[nt] = *(const short8*)(sBh + boff[nt]);
                bl[nt] = *(const short8*)(sBl + boff[nt]);
            }
            #pragma unroll
            for (int mt = 0; mt < 2; mt++)
                #pragma unroll
                for (int nt = 0; nt < 2; nt++) {
                    acc[mt][nt] = __builtin_amdgcn_mfma_f32_16x16x32_bf16(ah[mt], bh[nt], acc[mt][nt], 0, 0, 0);
                    acc[mt][nt] = __builtin_amdgcn_mfma_f32_16x16x32_bf16(ah[mt], bl[nt], acc[mt][nt], 0, 0, 0);
                    acc[mt][nt] = __builtin_amdgcn_mfma_f32_16x16x32_bf16(al[mt], bh[nt], acc[mt][nt], 0, 0, 0);
                }
            __syncthreads();
        }
        #pragma unroll
        for (int mt = 0; mt < 2; mt++)
            #pragma unroll
            for (int nt = 0; nt < 2; nt++) {
                int n = n0 + wn + nt * 16 + l16;
                float bv = b1[n];
                #pragma unroll
                for (int r = 0; r < 4; r++) {
                    int m = m0 + wm + mt * 16 + quad * 4 + r;
                    float z = acc[mt][nt][r] + bv;
                    size_t idx = (size_t)m * D1 + n;
                    dists[idx] = fabsf(z);          // rn1 division deferred to topk
                    m1q[idx] = (z > 0.f) ? 0xFFu : 0u;
                    float h = z > 0.f ? z : 0.f;
                    unsigned short hh = f2bf(h);
                    h1hi[idx] = hh;
                    h1lo[idx] = f2bf(h - bf2f(hh));
                }
            }
        return;
    }
    if (blk < 448) {                                   // zero region (float4)
        if (blk == 64 && t == 0) outp[0] = 0.f;
        int i4 = (blk - 64) * 1024 + t * 4;
        *(float4*)(zeros + i4) = make_float4(0.f, 0.f, 0.f, 0.f);
        return;
    }
    if (blk < 480) {                                   // W1 col quant -> W1Ti8
        int ty = t >> 5, tx = t & 31;
        int d = (blk - 448) * 8 + ty;
        float m = 0.f;
        for (int i = tx; i < D1; i += 32) m = fmaxf(m, fabsf(W1[(size_t)i * D + d]));
        #pragma unroll
        for (int off = 16; off > 0; off >>= 1) m = fmaxf(m, __shfl_down(m, off, 32));
        m = __shfl(m, 0, 32);
        m = fmaxf(m, 1e-20f);
        if (tx == 0) saq[d] = m / 127.f;
        float inv = 127.f / m;
        for (int i = tx; i < D1; i += 32) {
            int q = __float2int_rn(W1[(size_t)i * D + d] * inv);
            W1Ti8[(size_t)d * D1 + i] = (signed char)q;
        }
        return;
    }
    if (blk < 608) {                     // W2 row quant + bf16 split (fused)
        int o = (blk - 480) * 4 + (t >> 6);
        int l = t & 63;
        const float* row = W2 + (size_t)o * D1;
        float4 v[4];
        #pragma unroll
        for (int jj = 0; jj < 4; jj++) v[jj] = *(const float4*)(row + jj * 256 + l * 4);
        float m = 0.f;
        #pragma unroll
        for (int jj = 0; jj < 4; jj++)
            m = fmaxf(m, fmaxf(fmaxf(fabsf(v[jj].x), fabsf(v[jj].y)),
                               fmaxf(fabsf(v[jj].z), fabsf(v[jj].w))));
        m = waveReduceMax(m);
        m = __shfl(m, 0, 64);
        m = fmaxf(m, 1e-20f);
        if (l == 0) sbq[o] = m / 127.f;
        float inv = 127.f / m;
        #pragma unroll
        for (int jj = 0; jj < 4; jj++) {
            int base = jj * 256 + l * 4;
            int q0 = __float2int_rn(v[jj].x * inv);
            int q1 = __float2int_rn(v[jj].y * inv);
            int q2 = __float2int_rn(v[jj].z * inv);
            int q3 = __float2int_rn(v[jj].w * inv);
            unsigned int pk = (unsigned)(q0 & 255) | ((unsigned)(q1 & 255) << 8) |
                              ((unsigned)(q2 & 255) << 16) | ((unsigned)(q3 & 255) << 24);
            *(unsigned int*)(W2i8 + (size_t)o * D1 + base) = pk;
            ushort4 h, lo;
            h.x = f2bf(v[jj].x); lo.x = f2bf(v[jj].x - bf2f(h.x));
            h.y = f2bf(v[jj].y); lo.y = f2bf(v[jj].y - bf2f(h.y));
            h.z = f2bf(v[jj].z); lo.z = f2bf(v[jj].z - bf2f(h.z));
            h.w = f2bf(v[jj].w); lo.w = f2bf(v[jj].w - bf2f(h.w));
            *(ushort4*)(W2hi + (size_t)o * D1 + base) = h;
            *(ushort4*)(W2lo + (size_t)o * D1 + base) = lo;
        }
        return;
    }
    if (blk < 672) {                     // W3 row quant + bf16 split (fused)
        int p = (blk - 608) * 4 + (t >> 6);
        int l = t & 63;
        const float* row = W3 + (size_t)p * D2;
        float4 v[2];
        #pragma unroll
        for (int jj = 0; jj < 2; jj++) v[jj] = *(const float4*)(row + jj * 256 + l * 4);
        float m = 0.f;
        #pragma unroll
        for (int jj = 0; jj < 2; jj++)
            m = fmaxf(m, fmaxf(fmaxf(fabsf(v[jj].x), fabsf(v[jj].y)),
                               fmaxf(fabsf(v[jj].z), fabsf(v[jj].w))));
        m = waveReduceMax(m);
        m = __shfl(m, 0, 64);
        m = fmaxf(m, 1e-20f);
        if (l == 0) s3q[p] = m / 127.f;
        float inv = 127.f / m;
        #pragma unroll
        for (int jj = 0; jj < 2; jj++) {
            int base = jj * 256 + l * 4;
            int q0 = __float2int_rn(v[jj].x * inv);
            int q1 = __float2int_rn(v[jj].y * inv);
            int q2 = __float2int_rn(v[jj].z * inv);
            int q3 = __float2int_rn(v[jj].w * inv);
            unsigned int pk = (unsigned)(q0 & 255) | ((unsigned)(q1 & 255) << 8) |
                              ((unsigned)(q2 & 255) << 16) | ((unsigned)(q3 & 255) << 24);
            *(unsigned int*)(W3i8 + (size_t)p * D2 + base) = pk;
            ushort4 h, lo;
            h.x = f2bf(v[jj].x); lo.x = f2bf(v[jj].x - bf2f(h.x));
            h.y = f2bf(v[jj].y); lo.y = f2bf(v[jj].y - bf2f(h.y));
            h.z = f2bf(v[jj].z); lo.z = f2bf(v[jj].z - bf2f(h.z));
            h.w = f2bf(v[jj].w); lo.w = f2bf(v[jj].w - bf2f(h.w));
            *(ushort4*)(W3hi + (size_t)p * D2 + base) = h;
            *(ushort4*)(W3lo + (size_t)p * D2 + base) = lo;
        }
        return;
    }
    {                                                  // rn1 (256 blks, topk-only)
        int gw = (blk - 672) * 4 + (t >> 6);
        int lane = t & 63;
        const float* row = W1 + (size_t)gw * D;
        float s = 0.f;
        for (int tt = lane; tt < D; tt += 64) { float v = row[tt]; s += v * v; }
        s = waveReduceSum(s);
        if (lane == 0) rn1[gw] = sqrtf(s);
    }
}

// ---- merged dispatch 2: l2a (blocks 0..127) || gemm1 (128..1151) -----------
// gemm1: 128d x 64o, G=4 + counted-vmcnt dbuf, A-side mask (session best:
// ~45us k_big1, ~159us total). FROZEN — final configuration.
__global__ __launch_bounds__(256, 2) void k_big1(
    const unsigned short* __restrict__ h1hi, const unsigned short* __restrict__ h1lo,
    const unsigned short* __restrict__ W2hi, const unsigned short* __restrict__ W2lo,
    float* __restrict__ z2,
    const signed char* __restrict__ W1Ti8,   // [256][1024]  A rows (d)
    const signed char* __restrict__ W2i8,    // [512][1024]  B rows (o)
    const unsigned char* __restrict__ m1q,   // [B][1024]
    const float* __restrict__ saq,           // [256]
    const float* __restrict__ sbq,           // [512]
    signed char* __restrict__ qV2,           // [256][256][512] (d-major)
    float* __restrict__ norm2) {             // [B][512]
    __shared__ __align__(16) unsigned char smem[53248]; // 2x24K dbuf + 4K masks
    int bid = blockIdx.x;

    if (bid < 128) {
        // ---- l2a: split-K partial z2 (atomic; bias folded downstream) ----
        unsigned short* sm = (unsigned short*)smem;
        int m0 = (bid & 3) * 64, n0 = ((bid >> 2) & 7) * 64, k0 = (bid >> 5) * 256;
        f32x4 acc[2][2] = {};
        mfma3_64<D1, 256>(h1hi, h1lo, W2hi, W2lo, m0, n0, k0, sm, acc);
        int l = threadIdx.x & 63, w = threadIdx.x >> 6;
        int quad = l >> 4, l16 = l & 15;
        int wm = (w >> 1) * 32, wn = (w & 1) * 32;
        #pragma unroll
        for (int mt = 0; mt < 2; mt++)
            #pragma unroll
            for (int nt = 0; nt < 2; nt++) {
                int n = n0 + wn + nt * 16 + l16;
                #pragma unroll
                for (int r = 0; r < 4; r++) {
                    int m = m0 + wm + mt * 16 + quad * 4 + r;
                    atomicAdd(&z2[(size_t)m * D2 + n], acc[mt][nt][r]);
                }
            }
        return;
    }

    // ---- gemm1 (i8, BK=128, 128d x 64o, G=4; counted-vmcnt dbuf) ----
    int j = bid - 128;                 // 0..1023
    unsigned char* mbuf = (unsigned char*)smem + 49152;  // [4][1024] masks
    int m0 = (j & 1) * 128;           // d tile
    int o0 = ((j >> 1) & 7) * 64;     // o tile
    int b0 = (j >> 4) * 4;            // first batch of quad
    int tid = threadIdx.x;
    int l = tid & 63, w = tid >> 6;
    int quad = l >> 4, l16 = l & 15;
    int wm = (w >> 1) * 64, wn = (w & 1) * 32;

    // stage 4 batches' mask rows (4 KB over 256 threads, 16 B each)
    *(int4*)(mbuf + tid * 16) = *(const int4*)(m1q + (size_t)b0 * D1 + tid * 16);

    const signed char* pa[4];
    const signed char* pb[2];
    int lrow = l >> 3, ls = l & 7;
    #pragma unroll
    for (int r = 0; r < 4; r++) {
        int row = r * 32 + w * 8 + lrow;
        int c = (ls + (row & 7)) & 7;
        pa[r] = W1Ti8 + (size_t)(m0 + row) * D1 + c * 16;
    }
    #pragma unroll
    for (int r = 0; r < 2; r++) {
        int row = r * 32 + w * 8 + lrow;
        int c = (ls + (row & 7)) & 7;
        pb[r] = W2i8 + (size_t)(o0 + row) * D1 + c * 16;
    }
    int aoff[4][2], boff[2][2];
    #pragma unroll
    for (int mt = 0; mt < 4; mt++) {
        int tr = wm + mt * 16 + l16;
        #pragma unroll
        for (int ks = 0; ks < 2; ks++)
            aoff[mt][ks] = tr * 128 + (((ks * 4 + quad) - (tr & 7)) & 7) * 16;
    }
    #pragma unroll
    for (int nt = 0; nt < 2; nt++) {
        int tr = wn + nt * 16 + l16;
        #pragma unroll
        for (int ks = 0; ks < 2; ks++)
            boff[nt][ks] = tr * 128 + (((ks * 4 + quad) - (tr & 7)) & 7) * 16;
    }

    i32x4 acc[4][4][2];
    #pragma unroll
    for (int g = 0; g < 4; g++)
        #pragma unroll
        for (int i = 0; i < 4; i++)
            #pragma unroll
            for (int jj = 0; jj < 2; jj++) acc[g][i][jj] = (i32x4)0;

    // prologue: tile 0 -> buf0; masks staged; one full drain
    {
        signed char* buf0 = (signed char*)smem;
        #pragma unroll
        for (int r = 0; r < 4; r++)
            gld16(pa[r], buf0 + r * 4096 + w * 1024);
        #pragma unroll
        for (int r = 0; r < 2; r++)
            gld16(pb[r], buf0 + 16384 + r * 4096 + w * 1024);
    }
    __syncthreads();

    for (int t = 0; t < 8; t++) {
        const signed char* bufc = (const signed char*)smem + (t & 1) * 24576;
        signed char* bufn = (signed char*)smem + ((t + 1) & 1) * 24576;
        if (t < 7) {
            int kn = (t + 1) * 128;
            #pragma unroll
            for (int r = 0; r < 4; r++)
                gld16(pa[r] + kn, bufn + r * 4096 + w * 1024);
            #pragma unroll
            for (int r = 0; r < 2; r++)
                gld16(pb[r] + kn, bufn + 16384 + r * 4096 + w * 1024);
            asm volatile("s_waitcnt vmcnt(6)" ::: "memory");
        } else {
            asm volatile("s_waitcnt vmcnt(0)" ::: "memory");
        }
        __builtin_amdgcn_s_barrier();       // all waves' tile-t loads landed
        __builtin_amdgcn_sched_barrier(0);  // pin: no ds_read hoisted above
        const signed char* As = bufc;
        const signed char* Bs = bufc + 16384;
        #pragma unroll
        for (int ks = 0; ks < 2; ks++) {
            i32x4 mv[4];
            #pragma unroll
            for (int g = 0; g < 4; g++)
                mv[g] = *(const i32x4*)(mbuf + g * 1024 + t * 128 + ks * 64 + quad * 16);
            i32x4 a[4], bq[2];
            #pragma unroll
            for (int mt = 0; mt < 4; mt++)
                a[mt] = *(const i32x4*)(As + aoff[mt][ks]);
            #pragma unroll
            for (int nt = 0; nt < 2; nt++)
                bq[nt] = *(const i32x4*)(Bs + boff[nt][ks]);
            #pragma unroll
            for (int g = 0; g < 4; g++) {
                #pragma unroll
                for (int mt = 0; mt < 4; mt++) {
                    i32x4 ag = a[mt] & mv[g];
                    #pragma unroll
                    for (int nt = 0; nt < 2; nt++)
                        acc[g][mt][nt] = __builtin_amdgcn_mfma_i32_16x16x64_i8(
                            ag, bq[nt], acc[g][mt][nt], 0, 0, 0);
                }
            }
        }
        // all reads of bufc complete (in regs) before any wave issues the
        // iter t+1 DMA writes that target this buffer
        __builtin_amdgcn_s_barrier();
    }

    // ---- fused epilogue per batch: single-pass cvt, sbv^2 factored out ----
    float sad[4][4];
    #pragma unroll
    for (int mt = 0; mt < 4; mt++)
        #pragma unroll
        for (int r = 0; r < 4; r++)
            sad[mt][r] = saq[m0 + wm + mt * 16 + quad * 4 + r];
    float sbv[2], sbdq[2];
    #pragma unroll
    for (int nt = 0; nt < 2; nt++) {
        sbv[nt] = sbq[o0 + wn + nt * 16 + l16];
        sbdq[nt] = sbv[nt] * (1.0f / CQ);
    }

    #pragma unroll
    for (int g = 0; g < 4; g++) {
        int bg = b0 + g;
        float nrm[2] = {0.f, 0.f};
        signed char* qb = qV2 + (size_t)bg * (D * D2);
        #pragma unroll
        for (int mt = 0; mt < 4; mt++) {
            int dbase = m0 + wm + mt * 16 + quad * 4;
            #pragma unroll
            for (int r = 0; r < 4; r++) {
                float sa = sad[mt][r];
                size_t rowoff = (size_t)(dbase + r) * D2;
                #pragma unroll
                for (int nt = 0; nt < 2; nt++) {
                    float tv = (float)acc[g][mt][nt][r];
                    float u = tv * sa;
                    nrm[nt] = fmaf(u, u, nrm[nt]);
                    int qi = __float2int_rn(tv * sbdq[nt]);
                    qi = max(-127, min(127, qi));
                    qb[rowoff + o0 + wn + nt * 16 + l16] = (signed char)qi;
                }
            }
        }
        #pragma unroll
        for (int nt = 0; nt < 2; nt++) {
            float s = nrm[nt] * (sbv[nt] * sbv[nt]);
            s += __shfl_down(s, 32, 64);
            s += __shfl_down(s, 16, 64);
            if (l < 16)
                atomicAdd(&norm2[(size_t)bg * D2 + o0 + wn + nt * 16 + l], s);
        }
    }
}

// ---- merged dispatch 3: l3a z2-direct (0..31) || gemm2 (32..1055) ----------
// (R5 exact: single-buffer 33 KB — proven best; frozen)
__global__ __launch_bounds__(256) void k_big2(
    const float* __restrict__ z2,            // [B][512] (bias NOT applied)
    const float* __restrict__ b2,            // [512]
    const unsigned short* __restrict__ W3hi, const unsigned short* __restrict__ W3lo,
    float* __restrict__ z3,
    const signed char* __restrict__ W3i8,    // [256][512]
    const signed char* __restrict__ qV2,     // [256][256][512]
    const float* __restrict__ saq,           // [256]
    const float* __restrict__ s3q,           // [256]
    float* __restrict__ norm3) {             // [B][256]
    __shared__ __align__(16) unsigned char smem[33280];  // 32K tiles + 512B mask
    int bid = blockIdx.x;
    int tid = threadIdx.x;

    if (bid < 32) {
        // ---- l3a: split-K partial z3; A = relu(z2+b2) hi/lo computed inline
        unsigned short* sAh = (unsigned short*)smem;
        unsigned short* sAl = sAh + 2048;
        unsigned short* sBh = sAh + 4096;
        unsigned short* sBl = sAh + 6144;
        int m0 = (bid & 3) * 64, n0 = ((bid >> 2) & 3) * 64, k0 = (bid >> 4) * 256;
        int l = tid & 63, w = tid >> 6;
        int rsub = l >> 2;
        int quad = l >> 4, l16 = l & 15;
        int wm = (w >> 1) * 32, wn = (w & 1) * 32;
        int rloc = w * 16 + rsub;
        int c = swz_src(rloc, l);
        const float* pz  = z2 + (size_t)(m0 + rloc) * D2 + k0 + c * 8;
        const float* pbi = b2 + k0 + c * 8;
        const unsigned short* pb = W3hi + (size_t)(n0 + rloc) * D2 + k0 + c * 8;
        ptrdiff_t dB = W3lo - W3hi;
        int aoff[2], boff[2];
        #pragma unroll
        for (int mt = 0; mt < 2; mt++) aoff[mt] = swz_frag(wm + mt * 16 + l16, quad);
        #pragma unroll
        for (int nt = 0; nt < 2; nt++) boff[nt] = swz_frag(wn + nt * 16 + l16, quad);
        int wrA = w * 512 + l * 8;
        f32x4 acc[2][2] = {};
        for (int kk = 0; kk < 256; kk += 32) {
            gld16(pb + kk,      sBh + w * 512);
            gld16(pb + dB + kk, sBl + w * 512);
            float4 za = *(const float4*)(pz + kk);
            float4 zb = *(const float4*)(pz + kk + 4);
            float4 ba = *(const float4*)(pbi + kk);
            float4 bb = *(const float4*)(pbi + kk + 4);
            float hv[8] = { za.x + ba.x, za.y + ba.y, za.z + ba.z, za.w + ba.w,
                            zb.x + bb.x, zb.y + bb.y, zb.z + bb.z, zb.w + bb.w };
            short8 h8, l8;
            #pragma unroll
            for (int q2 = 0; q2 < 8; q2++) {
                float h = hv[q2] > 0.f ? hv[q2] : 0.f;
                unsigned short hh = f2bf(h);
                h8[q2] = (short)hh;
                l8[q2] = (short)f2bf(h - bf2f(hh));
            }
            *(short8*)(sAh + wrA) = h8;
            *(short8*)(sAl + wrA) = l8;
            __syncthreads();
            short8 ah[2], al[2], bh[2], bl[2];
            #pragma unroll
            for (int mt = 0; mt < 2; mt++) {
                ah[mt] = *(const short8*)(sAh + aoff[mt]);
                al[mt] = *(const short8*)(sAl + aoff[mt]);
            }
            #pragma unroll
            for (int nt = 0; nt < 2; nt++) {
                bh[nt] = *(const short8*)(sBh + boff[nt]);
                bl[nt] = *(const short8*)(sBl + boff[nt]);
            }
            #pragma unroll
            for (int mt = 0; mt < 2; mt++)
                #pragma unroll
                for (int nt = 0; nt < 2; nt++) {
                    acc[mt][nt] = __builtin_amdgcn_mfma_f32_16x16x32_bf16(ah[mt], bh[nt], acc[mt][nt], 0, 0, 0);
                    acc[mt][nt] = __builtin_amdgcn_mfma_f32_16x16x32_bf16(ah[mt], bl[nt], acc[mt][nt], 0, 0, 0);
                    acc[mt][nt] = __builtin_amdgcn_mfma_f32_16x16x32_bf16(al[mt], bh[nt], acc[mt][nt], 0, 0, 0);
                }
            __syncthreads();
        }
        #pragma unroll
        for (int mt = 0; mt < 2; mt++)
            #pragma unroll
            for (int nt = 0; nt < 2; nt++) {
                int n = n0 + wn + nt * 16 + l16;
                #pragma unroll
                for (int r = 0; r < 4; r++) {
                    int m = m0 + wm + mt * 16 + quad * 4 + r;
                    atomicAdd(&z3[(size_t)m * D3 + n], acc[mt][nt][r]);
                }
            }
        return;
    }

    // ---- gemm2 (i8, BK=128): norm3; m2 mask from z2+b2 in LDS ----
    int j = bid - 32;
    signed char* As = (signed char*)smem;
    signed char* Bs = (signed char*)smem + 16384;
    unsigned char* mbuf = (unsigned char*)smem + 32768;  // 512 B
    int m0 = (j & 1) * 128;           // p
    int n0 = ((j >> 1) & 1) * 128;    // d
    int bc = j >> 2;                  // batch
    int l = tid & 63, w = tid >> 6;
    int quad = l >> 4, l16 = l & 15;
    int wm = (w >> 1) * 64, wn = (w & 1) * 64;
    const signed char* Bsrc = qV2 + (size_t)bc * (D * D2);

    {   // fill m2 mask row for this batch
        #pragma unroll
        for (int rr = 0; rr < 2; rr++) {
            int o = tid * 2 + rr;
            float z = z2[(size_t)bc * D2 + o] + b2[o];
            mbuf[o] = (z > 0.f) ? 0xFFu : 0u;
        }
    }
    __syncthreads();

    const signed char* pa[4];
    const signed char* pb[4];
    int lrow = l >> 3, ls = l & 7;
    #pragma unroll
    for (int r = 0; r < 4; r++) {
        int row = r * 32 + w * 8 + lrow;
        int c = (ls + (row & 7)) & 7;
        pa[r] = W3i8 + (size_t)(m0 + row) * D2 + c * 16;
        pb[r] = Bsrc + (size_t)(n0 + row) * D2 + c * 16;
    }
    int aoff[4][2], boff[4][2];
    #pragma unroll
    for (int mt = 0; mt < 4; mt++) {
        int tr = wm + mt * 16 + l16;
        #pragma unroll
        for (int ks = 0; ks < 2; ks++)
            aoff[mt][ks] = tr * 128 + (((ks * 4 + quad) - (tr & 7)) & 7) * 16;
    }
    #pragma unroll
    for (int nt = 0; nt < 4; nt++) {
        int tr = wn + nt * 16 + l16;
        #pragma unroll
        for (int ks = 0; ks < 2; ks++)
            boff[nt][ks] = tr * 128 + (((ks * 4 + quad) - (tr & 7)) & 7) * 16;
    }

    i32x4 acc[4][4];
    #pragma unroll
    for (int i = 0; i < 4; i++)
        #pragma unroll
        for (int jj = 0; jj < 4; jj++) acc[i][jj] = (i32x4)0;

    for (int kk = 0; kk < D2; kk += 128) {
        #pragma unroll
        for (int r = 0; r < 4; r++) {
            gld16(pa[r] + kk, As + r * 4096 + w * 1024);
            gld16(pb[r] + kk, Bs + r * 4096 + w * 1024);
        }
        __syncthreads();
        i32x4 mv0 = *(const i32x4*)(mbuf + kk + quad * 16);
        i32x4 mv1 = *(const i32x4*)(mbuf + kk + 64 + quad * 16);
        #pragma unroll
        for (int ks = 0; ks < 2; ks++) {
            i32x4 mv = ks ? mv1 : mv0;
            i32x4 a[4], bq[4];
            #pragma unroll
            for (int mt = 0; mt < 4; mt++)
                a[mt] = *(const i32x4*)(As + aoff[mt][ks]);
            #pragma unroll
            for (int nt = 0; nt < 4; nt++)
                bq[nt] = (*(const i32x4*)(Bs + boff[nt][ks])) & mv;
            #pragma unroll
            for (int mt = 0; mt < 4; mt++)
                #pragma unroll
                for (int nt = 0; nt < 4; nt++)
                    acc[mt][nt] = __builtin_amdgcn_mfma_i32_16x16x64_i8(
                        a[mt], bq[nt], acc[mt][nt], 0, 0, 0);
        }
        __syncthreads();
    }

    float saCQ[4];
    #pragma unroll
    for (int nt = 0; nt < 4; nt++)
        saCQ[nt] = saq[n0 + wn + nt * 16 + l16] * CQ;

    #pragma unroll
    for (int mt = 0; mt < 4; mt++)
        #pragma unroll
        for (int r = 0; r < 4; r++) {
            float s = 0.f;
            #pragma unroll
            for (int nt = 0; nt < 4; nt++) {
                float v = (float)acc[mt][nt][r] * saCQ[nt];
                s += v * v;
            }
            s += __shfl_down(s, 8, 64);
            s += __shfl_down(s, 4, 64);
            s += __shfl_down(s, 2, 64);
            s += __shfl_down(s, 1, 64);
            if (l16 == 0) {
                int p = m0 + wm + mt * 16 + quad * 4 + r;
                float s3 = s3q[p];
                atomicAdd(&norm3[(size_t)bc * D3 + p], s * s3 * s3);
            }
        }
}

// ---- wave-per-batch k-smallest sum (dist1 = |z1|/rn1 computed inline) ------
__global__ __launch_bounds__(256) void k_topk(
    const float* __restrict__ dists,    // [B][D1] |z1| only
    const float* __restrict__ rn1,      // [D1]
    const float* __restrict__ z2, const float* __restrict__ b2,
    const float* __restrict__ norm2,
    const float* __restrict__ z3, const float* __restrict__ b3,
    const float* __restrict__ norm3,
    const int* __restrict__ kp, float* __restrict__ outp) {
    int t = threadIdx.x;
    int wv = t >> 6, lane = t & 63;
    int b = blockIdx.x * 4 + wv;
    float lv[28];
    #pragma unroll
    for (int j = 0; j < 16; j++) {
        int n = lane + 64 * j;
        lv[j] = dists[(size_t)b * D1 + n] / rn1[n];
    }
    #pragma unroll
    for (int j = 16; j < 24; j++) {
        int o = lane + 64 * (j - 16);
        float zz = z2[(size_t)b * D2 + o] + b2[o];
        lv[j] = fabsf(zz) / sqrtf(norm2[(size_t)b * D2 + o]);
    }
    #pragma unroll
    for (int j = 24; j < 28; j++) {
        int p = lane + 64 * (j - 24);
        float zz = z3[(size_t)b * D3 + p] + b3[p];
        lv[j] = fabsf(zz) / sqrtf(norm3[(size_t)b * D3 + p]);
    }
    int k = *kp;
    if (k > NDIST) k = NDIST;
    float sum = 0.f;
    for (int it = 0; it < k; it++) {
        float mv = lv[0]; int mj = 0;
        #pragma unroll
        for (int j = 1; j < 28; j++)
            if (lv[j] < mv) { mv = lv[j]; mj = j; }
        unsigned long long key =
            ((unsigned long long)__float_as_uint(mv) << 32) | (unsigned)(lane * 32 + mj);
        #pragma unroll
        for (int off = 1; off < 64; off <<= 1) {
            unsigned long long o = __shfl_xor(key, off, 64);
            if (o < key) key = o;
        }
        sum += __uint_as_float((unsigned)(key >> 32));
        int wl = (int)((key >> 5) & 63u), wj = (int)(key & 31u);
        if (lane == wl) lv[wj] = FLT_MAX;
    }
    if (lane == 0) atomicAdd(outp, sum);
}

extern "C" void kernel_launch(void* const* d_in, const int* in_sizes, int n_in,
                              void* d_out, int out_size, void* d_ws, size_t ws_size,
                              hipStream_t stream) {
    const float* x  = (const float*)d_in[0];
    const float* W1 = (const float*)d_in[1];
    const float* b1 = (const float*)d_in[2];
    const float* W2 = (const float*)d_in[3];
    const float* b2 = (const float*)d_in[4];
    const float* W3 = (const float*)d_in[5];
    const float* b3 = (const float*)d_in[6];
    const int*   kp = (const int*)d_in[7];
    float* outp = (float*)d_out;

    float* fp = (float*)d_ws;
    float* rn1     = fp;                          fp += D1;
    float* dists   = fp;                          fp += (size_t)B * D1;
    float* saq     = fp;                          fp += D;
    float* sbq     = fp;                          fp += D2;
    float* s3q     = fp;                          fp += D3;
    // zero region: z2 || z3 || norm2 || norm3 (contiguous, 393216 floats)
    float* z2      = fp;                          fp += (size_t)B * D2;
    float* z3      = fp;                          fp += (size_t)B * D3;
    float* norm2   = fp;                          fp += (size_t)B * D2;
    float* norm3   = fp;                          fp += (size_t)B * D3;
    unsigned short* up = (unsigned short*)fp;
    unsigned short* W2hi  = up;  up += (size_t)D2 * D1;
    unsigned short* W2lo  = up;  up += (size_t)D2 * D1;
    unsigned short* W3hi  = up;  up += (size_t)D3 * D2;
    unsigned short* W3lo  = up;  up += (size_t)D3 * D2;
    unsigned short* h1hi  = up;  up += (size_t)B * D1;
    unsigned short* h1lo  = up;  up += (size_t)B * D1;
    signed char*    cp = (signed char*)up;
    signed char*    W1Ti8 = cp;  cp += (size_t)D * D1;
    signed char*    W2i8  = cp;  cp += (size_t)D2 * D1;
    signed char*    W3i8  = cp;  cp += (size_t)D3 * D2;
    unsigned char*  m1q   = (unsigned char*)cp;  cp += (size_t)B * D1;
    signed char*    qV2   = cp;   // full 256-batch (33.5 MB; ws proven since R10)

    // l1 gemm (64) + zeros (384) + W1 quant (32) + fused W2 quant+split (128)
    // + fused W3 quant+split (64) + rn1 (256) = 928 blocks
    k_l1p<<<928, 256, 0, stream>>>(x, W1, W2, W3, b1,
                                   dists, m1q, h1hi, h1lo,
                                   z2, outp, W2hi, W2lo, W3hi, W3lo,
                                   W1Ti8, saq, W2i8, sbq, W3i8, s3q, rn1);

    // l2a (128) || gemm1 (1024, 128d x 64o, G=4, counted-vmcnt dbuf, A-mask)
    k_big1<<<1152, 256, 0, stream>>>(h1hi, h1lo, W2hi, W2lo, z2,
                                     W1Ti8, W2i8, m1q, saq, sbq, qV2, norm2);

    // l3a z2-direct (32) || gemm2 single-buffer (R5 exact)
    k_big2<<<1056, 256, 0, stream>>>(z2, b2, W3hi, W3lo, z3,
                                     W3i8, qV2, saq, s3q, norm3);

    k_topk<<<B / 4, 256, 0, stream>>>(dists, rn1, z2, b2, norm2, z3, b3, norm3,
                                      kp, outp);
}

// Round 24
// 159.986 us; speedup vs baseline: 1.0087x; 1.0026x over previous
//
#include <hip/hip_runtime.h>
#include <math.h>
#include <float.h>

#define B   256
#define D   256
#define D1  1024
#define D2  512
#define D3  256
#define NDIST (D1 + D2 + D3)   // 1792
#define CQ  2.0f               // qV2 static scale multiplier (step = sa[d]*CQ)

typedef __attribute__((ext_vector_type(8))) short short8;
typedef __attribute__((ext_vector_type(4))) float f32x4;
typedef __attribute__((ext_vector_type(4))) int   i32x4;

__device__ __forceinline__ float waveReduceSum(float v) {
    #pragma unroll
    for (int off = 32; off > 0; off >>= 1)
        v += __shfl_down(v, off, 64);
    return v;
}
__device__ __forceinline__ float waveReduceMax(float v) {
    #pragma unroll
    for (int off = 32; off > 0; off >>= 1)
        v = fmaxf(v, __shfl_down(v, off, 64));
    return v;
}
__device__ __forceinline__ unsigned short f2bf(float f) {
    unsigned int u = __float_as_uint(f);
    u = (u + 0x7FFFu + ((u >> 16) & 1u)) >> 16;   // RNE
    return (unsigned short)u;
}
__device__ __forceinline__ float bf2f(unsigned short h) {
    return __uint_as_float(((unsigned int)h) << 16);
}
__device__ __forceinline__ void gld16(const void* g, void* l) {
    __builtin_amdgcn_global_load_lds(
        (const __attribute__((address_space(1))) unsigned int*)g,
        (__attribute__((address_space(3))) unsigned int*)l, 16, 0, 0);
}
__device__ __forceinline__ int swz_src(int row, int lane) {
    return ((lane & 3) + ((row >> 1) & 3)) & 3;
}
__device__ __forceinline__ int swz_frag(int row, int quad) {
    return row * 32 + (((quad - ((row >> 1) & 3)) & 3) * 8);
}

// load 8 fp32, split to bf16 hi/lo short8
__device__ __forceinline__ void split8(const float* p, short8& h8, short8& l8) {
    float4 a = *(const float4*)(p);
    float4 b = *(const float4*)(p + 4);
    float hv[8] = { a.x, a.y, a.z, a.w, b.x, b.y, b.z, b.w };
    #pragma unroll
    for (int q = 0; q < 8; q++) {
        unsigned short hh = f2bf(hv[q]);
        h8[q] = (short)hh;
        l8[q] = (short)f2bf(hv[q] - bf2f(hh));
    }
}

// ---- compensated bf16 MFMA mainloop, 64x64 tile, K range [k0, k0+KL) -------
template <int KD, int KL>
__device__ __forceinline__ void mfma3_64(
    const unsigned short* __restrict__ Ahi, const unsigned short* __restrict__ Alo,
    const unsigned short* __restrict__ Bhi, const unsigned short* __restrict__ Blo,
    int m0, int n0, int k0, unsigned short* sm, f32x4 acc[2][2]) {
    int tid = threadIdx.x;
    int l = tid & 63, w = tid >> 6;
    int rsub = l >> 2;
    int quad = l >> 4, l16 = l & 15;
    int wm = (w >> 1) * 32, wn = (w & 1) * 32;
    unsigned short* sAh = sm;
    unsigned short* sAl = sm + 2048;
    unsigned short* sBh = sm + 4096;
    unsigned short* sBl = sm + 6144;
    ptrdiff_t dA = Alo - Ahi, dB = Blo - Bhi;
    int rloc = w * 16 + rsub;
    int c = swz_src(rloc, l);
    const unsigned short* pa = Ahi + (size_t)(m0 + rloc) * KD + k0 + c * 8;
    const unsigned short* pb = Bhi + (size_t)(n0 + rloc) * KD + k0 + c * 8;
    int aoff[2], boff[2];
    #pragma unroll
    for (int mt = 0; mt < 2; mt++) aoff[mt] = swz_frag(wm + mt * 16 + l16, quad);
    #pragma unroll
    for (int nt = 0; nt < 2; nt++) boff[nt] = swz_frag(wn + nt * 16 + l16, quad);
    for (int kk = 0; kk < KL; kk += 32) {
        gld16(pa + kk,      sAh + w * 512);
        gld16(pa + dA + kk, sAl + w * 512);
        gld16(pb + kk,      sBh + w * 512);
        gld16(pb + dB + kk, sBl + w * 512);
        __syncthreads();
        short8 ah[2], al[2], bh[2], bl[2];
        #pragma unroll
        for (int mt = 0; mt < 2; mt++) {
            ah[mt] = *(const short8*)(sAh + aoff[mt]);
            al[mt] = *(const short8*)(sAl + aoff[mt]);
        }
        #pragma unroll
        for (int nt = 0; nt < 2; nt++) {
            bh[nt] = *(const short8*)(sBh + boff[nt]);
            bl[nt] = *(const short8*)(sBl + boff[nt]);
        }
        #pragma unroll
        for (int mt = 0; mt < 2; mt++)
            #pragma unroll
            for (int nt = 0; nt < 2; nt++) {
                acc[mt][nt] = __builtin_amdgcn_mfma_f32_16x16x32_bf16(ah[mt], bh[nt], acc[mt][nt], 0, 0, 0);
                acc[mt][nt] = __builtin_amdgcn_mfma_f32_16x16x32_bf16(ah[mt], bl[nt], acc[mt][nt], 0, 0, 0);
                acc[mt][nt] = __builtin_amdgcn_mfma_f32_16x16x32_bf16(al[mt], bh[nt], acc[mt][nt], 0, 0, 0);
            }
        __syncthreads();
    }
}

// ---- dispatch 1: l1 gemm + zeros + fused quant+split jobs + rn1 ------------
__global__ __launch_bounds__(256) void k_l1p(
    const float* __restrict__ x, const float* __restrict__ W1,
    const float* __restrict__ W2, const float* __restrict__ W3,
    const float* __restrict__ b1,
    float* __restrict__ dists, unsigned char* __restrict__ m1q,
    unsigned short* __restrict__ h1hi, unsigned short* __restrict__ h1lo,
    float* __restrict__ zeros, float* __restrict__ outp,
    unsigned short* __restrict__ W2hi, unsigned short* __restrict__ W2lo,
    unsigned short* __restrict__ W3hi, unsigned short* __restrict__ W3lo,
    signed char* __restrict__ W1Ti8, float* __restrict__ saq,
    signed char* __restrict__ W2i8,  float* __restrict__ sbq,
    signed char* __restrict__ W3i8,  float* __restrict__ s3q,
    float* __restrict__ rn1) {
    __shared__ __align__(16) unsigned short sm[8192];
    int blk = blockIdx.x;
    int t = threadIdx.x;

    if (blk < 64) {          // l1: z1 GEMM; A=x, B=W1 staged fp32->hi/lo
        unsigned short* sAh = sm;
        unsigned short* sAl = sm + 2048;
        unsigned short* sBh = sm + 4096;
        unsigned short* sBl = sm + 6144;
        int m0 = (blk & 3) * 64, n0 = (blk >> 2) * 64;
        int l = t & 63, w = t >> 6;
        int rsub = l >> 2;
        int quad = l >> 4, l16 = l & 15;
        int wm = (w >> 1) * 32, wn = (w & 1) * 32;
        int rloc = w * 16 + rsub;
        int c = swz_src(rloc, l);
        const float* pax = x + (size_t)(m0 + rloc) * D + c * 8;
        const float* pbw = W1 + (size_t)(n0 + rloc) * D + c * 8;
        int aoff[2], boff[2];
        #pragma unroll
        for (int mt = 0; mt < 2; mt++) aoff[mt] = swz_frag(wm + mt * 16 + l16, quad);
        #pragma unroll
        for (int nt = 0; nt < 2; nt++) boff[nt] = swz_frag(wn + nt * 16 + l16, quad);
        int wrA = w * 512 + l * 8;
        f32x4 acc[2][2] = {};
        for (int kk = 0; kk < D; kk += 32) {
            short8 ha, la, hb, lb;
            split8(pax + kk, ha, la);
            split8(pbw + kk, hb, lb);
            *(short8*)(sAh + wrA) = ha;
            *(short8*)(sAl + wrA) = la;
            *(short8*)(sBh + wrA) = hb;
            *(short8*)(sBl + wrA) = lb;
            __syncthreads();
            short8 ah[2], al[2], bh[2], bl[2];
            #pragma unroll
            for (int mt = 0; mt < 2; mt++) {
                ah[mt] = *(const short8*)(sAh + aoff[mt]);
                al[mt] = *(const short8*)(sAl + aoff[mt]);
            }
            #pragma unroll
            for (int nt = 0; nt < 2; nt++) {
                bh[nt] = *(const short8*)(sBh + boff[nt]);
                bl[nt] = *(const short8*)(sBl + boff[nt]);
            }
            #pragma unroll
            for (int mt = 0; mt < 2; mt++)
                #pragma unroll
                for (int nt = 0; nt < 2; nt++) {
                    acc[mt][nt] = __builtin_amdgcn_mfma_f32_16x16x32_bf16(ah[mt], bh[nt], acc[mt][nt], 0, 0, 0);
                    acc[mt][nt] = __builtin_amdgcn_mfma_f32_16x16x32_bf16(ah[mt], bl[nt], acc[mt][nt], 0, 0, 0);
                    acc[mt][nt] = __builtin_amdgcn_mfma_f32_16x16x32_bf16(al[mt], bh[nt], acc[mt][nt], 0, 0, 0);
                }
            __syncthreads();
        }
        #pragma unroll
        for (int mt = 0; mt < 2; mt++)
            #pragma unroll
            for (int nt = 0; nt < 2; nt++) {
                int n = n0 + wn + nt * 16 + l16;
                float bv = b1[n];
                #pragma unroll
                for (int r = 0; r < 4; r++) {
                    int m = m0 + wm + mt * 16 + quad * 4 + r;
                    float z = acc[mt][nt][r] + bv;
                    size_t idx = (size_t)m * D1 + n;
                    dists[idx] = fabsf(z);          // rn1 division deferred to topk
                    m1q[idx] = (z > 0.f) ? 0xFFu : 0u;
                    float h = z > 0.f ? z : 0.f;
                    unsigned short hh = f2bf(h);
                    h1hi[idx] = hh;
                    h1lo[idx] = f2bf(h - bf2f(hh));
                }
            }
        return;
    }
    if (blk < 448) {                                   // zero region (float4)
        if (blk == 64 && t == 0) outp[0] = 0.f;
        int i4 = (blk - 64) * 1024 + t * 4;
        *(float4*)(zeros + i4) = make_float4(0.f, 0.f, 0.f, 0.f);
        return;
    }
    if (blk < 480) {                                   // W1 col quant -> W1Ti8
        int ty = t >> 5, tx = t & 31;
        int d = (blk - 448) * 8 + ty;
        float m = 0.f;
        for (int i = tx; i < D1; i += 32) m = fmaxf(m, fabsf(W1[(size_t)i * D + d]));
        #pragma unroll
        for (int off = 16; off > 0; off >>= 1) m = fmaxf(m, __shfl_down(m, off, 32));
        m = __shfl(m, 0, 32);
        m = fmaxf(m, 1e-20f);
        if (tx == 0) saq[d] = m / 127.f;
        float inv = 127.f / m;
        for (int i = tx; i < D1; i += 32) {
            int q = __float2int_rn(W1[(size_t)i * D + d] * inv);
            W1Ti8[(size_t)d * D1 + i] = (signed char)q;
        }
        return;
    }
    if (blk < 608) {                     // W2 row quant + bf16 split (fused)
        int o = (blk - 480) * 4 + (t >> 6);
        int l = t & 63;
        const float* row = W2 + (size_t)o * D1;
        float4 v[4];
        #pragma unroll
        for (int jj = 0; jj < 4; jj++) v[jj] = *(const float4*)(row + jj * 256 + l * 4);
        float m = 0.f;
        #pragma unroll
        for (int jj = 0; jj < 4; jj++)
            m = fmaxf(m, fmaxf(fmaxf(fabsf(v[jj].x), fabsf(v[jj].y)),
                               fmaxf(fabsf(v[jj].z), fabsf(v[jj].w))));
        m = waveReduceMax(m);
        m = __shfl(m, 0, 64);
        m = fmaxf(m, 1e-20f);
        if (l == 0) sbq[o] = m / 127.f;
        float inv = 127.f / m;
        #pragma unroll
        for (int jj = 0; jj < 4; jj++) {
            int base = jj * 256 + l * 4;
            int q0 = __float2int_rn(v[jj].x * inv);
            int q1 = __float2int_rn(v[jj].y * inv);
            int q2 = __float2int_rn(v[jj].z * inv);
            int q3 = __float2int_rn(v[jj].w * inv);
            unsigned int pk = (unsigned)(q0 & 255) | ((unsigned)(q1 & 255) << 8) |
                              ((unsigned)(q2 & 255) << 16) | ((unsigned)(q3 & 255) << 24);
            *(unsigned int*)(W2i8 + (size_t)o * D1 + base) = pk;
            ushort4 h, lo;
            h.x = f2bf(v[jj].x); lo.x = f2bf(v[jj].x - bf2f(h.x));
            h.y = f2bf(v[jj].y); lo.y = f2bf(v[jj].y - bf2f(h.y));
            h.z = f2bf(v[jj].z); lo.z = f2bf(v[jj].z - bf2f(h.z));
            h.w = f2bf(v[jj].w); lo.w = f2bf(v[jj].w - bf2f(h.w));
            *(ushort4*)(W2hi + (size_t)o * D1 + base) = h;
            *(ushort4*)(W2lo + (size_t)o * D1 + base) = lo;
        }
        return;
    }
    if (blk < 672) {                     // W3 row quant + bf16 split (fused)
        int p = (blk - 608) * 4 + (t >> 6);
        int l = t & 63;
        const float* row = W3 + (size_t)p * D2;
        float4 v[2];
        #pragma unroll
        for (int jj = 0; jj < 2; jj++) v[jj] = *(const float4*)(row + jj * 256 + l * 4);
        float m = 0.f;
        #pragma unroll
        for (int jj = 0; jj < 2; jj++)
            m = fmaxf(m, fmaxf(fmaxf(fabsf(v[jj].x), fabsf(v[jj].y)),
                               fmaxf(fabsf(v[jj].z), fabsf(v[jj].w))));
        m = waveReduceMax(m);
        m = __shfl(m, 0, 64);
        m = fmaxf(m, 1e-20f);
        if (l == 0) s3q[p] = m / 127.f;
        float inv = 127.f / m;
        #pragma unroll
        for (int jj = 0; jj < 2; jj++) {
            int base = jj * 256 + l * 4;
            int q0 = __float2int_rn(v[jj].x * inv);
            int q1 = __float2int_rn(v[jj].y * inv);
            int q2 = __float2int_rn(v[jj].z * inv);
            int q3 = __float2int_rn(v[jj].w * inv);
            unsigned int pk = (unsigned)(q0 & 255) | ((unsigned)(q1 & 255) << 8) |
                              ((unsigned)(q2 & 255) << 16) | ((unsigned)(q3 & 255) << 24);
            *(unsigned int*)(W3i8 + (size_t)p * D2 + base) = pk;
            ushort4 h, lo;
            h.x = f2bf(v[jj].x); lo.x = f2bf(v[jj].x - bf2f(h.x));
            h.y = f2bf(v[jj].y); lo.y = f2bf(v[jj].y - bf2f(h.y));
            h.z = f2bf(v[jj].z); lo.z = f2bf(v[jj].z - bf2f(h.z));
            h.w = f2bf(v[jj].w); lo.w = f2bf(v[jj].w - bf2f(h.w));
            *(ushort4*)(W3hi + (size_t)p * D2 + base) = h;
            *(ushort4*)(W3lo + (size_t)p * D2 + base) = lo;
        }
        return;
    }
    {                                                  // rn1 (256 blks, topk-only)
        int gw = (blk - 672) * 4 + (t >> 6);
        int lane = t & 63;
        const float* row = W1 + (size_t)gw * D;
        float s = 0.f;
        for (int tt = lane; tt < D; tt += 64) { float v = row[tt]; s += v * v; }
        s = waveReduceSum(s);
        if (lane == 0) rn1[gw] = sqrtf(s);
    }
}

// ---- merged dispatch 2: l2a (blocks 0..127) || gemm1 (128..1151) -----------
// gemm1: 128d x 64o, G=4 + counted-vmcnt dbuf, A-side mask (session best:
// ~45us k_big1, ~159us total). FROZEN — final configuration.
__global__ __launch_bounds__(256, 2) void k_big1(
    const unsigned short* __restrict__ h1hi, const unsigned short* __restrict__ h1lo,
    const unsigned short* __restrict__ W2hi, const unsigned short* __restrict__ W2lo,
    float* __restrict__ z2,
    const signed char* __restrict__ W1Ti8,   // [256][1024]  A rows (d)
    const signed char* __restrict__ W2i8,    // [512][1024]  B rows (o)
    const unsigned char* __restrict__ m1q,   // [B][1024]
    const float* __restrict__ saq,           // [256]
    const float* __restrict__ sbq,           // [512]
    signed char* __restrict__ qV2,           // [256][256][512] (d-major)
    float* __restrict__ norm2) {             // [B][512]
    __shared__ __align__(16) unsigned char smem[53248]; // 2x24K dbuf + 4K masks
    int bid = blockIdx.x;

    if (bid < 128) {
        // ---- l2a: split-K partial z2 (atomic; bias folded downstream) ----
        unsigned short* sm = (unsigned short*)smem;
        int m0 = (bid & 3) * 64, n0 = ((bid >> 2) & 7) * 64, k0 = (bid >> 5) * 256;
        f32x4 acc[2][2] = {};
        mfma3_64<D1, 256>(h1hi, h1lo, W2hi, W2lo, m0, n0, k0, sm, acc);
        int l = threadIdx.x & 63, w = threadIdx.x >> 6;
        int quad = l >> 4, l16 = l & 15;
        int wm = (w >> 1) * 32, wn = (w & 1) * 32;
        #pragma unroll
        for (int mt = 0; mt < 2; mt++)
            #pragma unroll
            for (int nt = 0; nt < 2; nt++) {
                int n = n0 + wn + nt * 16 + l16;
                #pragma unroll
                for (int r = 0; r < 4; r++) {
                    int m = m0 + wm + mt * 16 + quad * 4 + r;
                    atomicAdd(&z2[(size_t)m * D2 + n], acc[mt][nt][r]);
                }
            }
        return;
    }

    // ---- gemm1 (i8, BK=128, 128d x 64o, G=4; counted-vmcnt dbuf) ----
    int j = bid - 128;                 // 0..1023
    unsigned char* mbuf = (unsigned char*)smem + 49152;  // [4][1024] masks
    int m0 = (j & 1) * 128;           // d tile
    int o0 = ((j >> 1) & 7) * 64;     // o tile
    int b0 = (j >> 4) * 4;            // first batch of quad
    int tid = threadIdx.x;
    int l = tid & 63, w = tid >> 6;
    int quad = l >> 4, l16 = l & 15;
    int wm = (w >> 1) * 64, wn = (w & 1) * 32;

    // stage 4 batches' mask rows (4 KB over 256 threads, 16 B each)
    *(int4*)(mbuf + tid * 16) = *(const int4*)(m1q + (size_t)b0 * D1 + tid * 16);

    const signed char* pa[4];
    const signed char* pb[2];
    int lrow = l >> 3, ls = l & 7;
    #pragma unroll
    for (int r = 0; r < 4; r++) {
        int row = r * 32 + w * 8 + lrow;
        int c = (ls + (row & 7)) & 7;
        pa[r] = W1Ti8 + (size_t)(m0 + row) * D1 + c * 16;
    }
    #pragma unroll
    for (int r = 0; r < 2; r++) {
        int row = r * 32 + w * 8 + lrow;
        int c = (ls + (row & 7)) & 7;
        pb[r] = W2i8 + (size_t)(o0 + row) * D1 + c * 16;
    }
    int aoff[4][2], boff[2][2];
    #pragma unroll
    for (int mt = 0; mt < 4; mt++) {
        int tr = wm + mt * 16 + l16;
        #pragma unroll
        for (int ks = 0; ks < 2; ks++)
            aoff[mt][ks] = tr * 128 + (((ks * 4 + quad) - (tr & 7)) & 7) * 16;
    }
    #pragma unroll
    for (int nt = 0; nt < 2; nt++) {
        int tr = wn + nt * 16 + l16;
        #pragma unroll
        for (int ks = 0; ks < 2; ks++)
            boff[nt][ks] = tr * 128 + (((ks * 4 + quad) - (tr & 7)) & 7) * 16;
    }

    i32x4 acc[4][4][2];
    #pragma unroll
    for (int g = 0; g < 4; g++)
        #pragma unroll
        for (int i = 0; i < 4; i++)
            #pragma unroll
            for (int jj = 0; jj < 2; jj++) acc[g][i][jj] = (i32x4)0;

    // prologue: tile 0 -> buf0; masks staged; one full drain
    {
        signed char* buf0 = (signed char*)smem;
        #pragma unroll
        for (int r = 0; r < 4; r++)
            gld16(pa[r], buf0 + r * 4096 + w * 1024);
        #pragma unroll
        for (int r = 0; r < 2; r++)
            gld16(pb[r], buf0 + 16384 + r * 4096 + w * 1024);
    }
    __syncthreads();

    for (int t = 0; t < 8; t++) {
        const signed char* bufc = (const signed char*)smem + (t & 1) * 24576;
        signed char* bufn = (signed char*)smem + ((t + 1) & 1) * 24576;
        if (t < 7) {
            int kn = (t + 1) * 128;
            #pragma unroll
            for (int r = 0; r < 4; r++)
                gld16(pa[r] + kn, bufn + r * 4096 + w * 1024);
            #pragma unroll
            for (int r = 0; r < 2; r++)
                gld16(pb[r] + kn, bufn + 16384 + r * 4096 + w * 1024);
            asm volatile("s_waitcnt vmcnt(6)" ::: "memory");
        } else {
            asm volatile("s_waitcnt vmcnt(0)" ::: "memory");
        }
        __builtin_amdgcn_s_barrier();       // all waves' tile-t loads landed
        __builtin_amdgcn_sched_barrier(0);  // pin: no ds_read hoisted above
        const signed char* As = bufc;
        const signed char* Bs = bufc + 16384;
        #pragma unroll
        for (int ks = 0; ks < 2; ks++) {
            i32x4 mv[4];
            #pragma unroll
            for (int g = 0; g < 4; g++)
                mv[g] = *(const i32x4*)(mbuf + g * 1024 + t * 128 + ks * 64 + quad * 16);
            i32x4 a[4], bq[2];
            #pragma unroll
            for (int mt = 0; mt < 4; mt++)
                a[mt] = *(const i32x4*)(As + aoff[mt][ks]);
            #pragma unroll
            for (int nt = 0; nt < 2; nt++)
                bq[nt] = *(const i32x4*)(Bs + boff[nt][ks]);
            #pragma unroll
            for (int g = 0; g < 4; g++) {
                #pragma unroll
                for (int mt = 0; mt < 4; mt++) {
                    i32x4 ag = a[mt] & mv[g];
                    #pragma unroll
                    for (int nt = 0; nt < 2; nt++)
                        acc[g][mt][nt] = __builtin_amdgcn_mfma_i32_16x16x64_i8(
                            ag, bq[nt], acc[g][mt][nt], 0, 0, 0);
                }
            }
        }
        // all reads of bufc complete (in regs) before any wave issues the
        // iter t+1 DMA writes that target this buffer
        __builtin_amdgcn_s_barrier();
    }

    // ---- fused epilogue per batch: single-pass cvt, sbv^2 factored out ----
    float sad[4][4];
    #pragma unroll
    for (int mt = 0; mt < 4; mt++)
        #pragma unroll
        for (int r = 0; r < 4; r++)
            sad[mt][r] = saq[m0 + wm + mt * 16 + quad * 4 + r];
    float sbv[2], sbdq[2];
    #pragma unroll
    for (int nt = 0; nt < 2; nt++) {
        sbv[nt] = sbq[o0 + wn + nt * 16 + l16];
        sbdq[nt] = sbv[nt] * (1.0f / CQ);
    }

    #pragma unroll
    for (int g = 0; g < 4; g++) {
        int bg = b0 + g;
        float nrm[2] = {0.f, 0.f};
        signed char* qb = qV2 + (size_t)bg * (D * D2);
        #pragma unroll
        for (int mt = 0; mt < 4; mt++) {
            int dbase = m0 + wm + mt * 16 + quad * 4;
            #pragma unroll
            for (int r = 0; r < 4; r++) {
                float sa = sad[mt][r];
                size_t rowoff = (size_t)(dbase + r) * D2;
                #pragma unroll
                for (int nt = 0; nt < 2; nt++) {
                    float tv = (float)acc[g][mt][nt][r];
                    float u = tv * sa;
                    nrm[nt] = fmaf(u, u, nrm[nt]);
                    int qi = __float2int_rn(tv * sbdq[nt]);
                    qi = max(-127, min(127, qi));
                    qb[rowoff + o0 + wn + nt * 16 + l16] = (signed char)qi;
                }
            }
        }
        #pragma unroll
        for (int nt = 0; nt < 2; nt++) {
            float s = nrm[nt] * (sbv[nt] * sbv[nt]);
            s += __shfl_down(s, 32, 64);
            s += __shfl_down(s, 16, 64);
            if (l < 16)
                atomicAdd(&norm2[(size_t)bg * D2 + o0 + wn + nt * 16 + l], s);
        }
    }
}

// ---- merged dispatch 3: l3a z2-direct (0..31) || gemm2 (32..1055) ----------
// (R5 exact: single-buffer 33 KB — proven best; frozen)
__global__ __launch_bounds__(256) void k_big2(
    const float* __restrict__ z2,            // [B][512] (bias NOT applied)
    const float* __restrict__ b2,            // [512]
    const unsigned short* __restrict__ W3hi, const unsigned short* __restrict__ W3lo,
    float* __restrict__ z3,
    const signed char* __restrict__ W3i8,    // [256][512]
    const signed char* __restrict__ qV2,     // [256][256][512]
    const float* __restrict__ saq,           // [256]
    const float* __restrict__ s3q,           // [256]
    float* __restrict__ norm3) {             // [B][256]
    __shared__ __align__(16) unsigned char smem[33280];  // 32K tiles + 512B mask
    int bid = blockIdx.x;
    int tid = threadIdx.x;

    if (bid < 32) {
        // ---- l3a: split-K partial z3; A = relu(z2+b2) hi/lo computed inline
        unsigned short* sAh = (unsigned short*)smem;
        unsigned short* sAl = sAh + 2048;
        unsigned short* sBh = sAh + 4096;
        unsigned short* sBl = sAh + 6144;
        int m0 = (bid & 3) * 64, n0 = ((bid >> 2) & 3) * 64, k0 = (bid >> 4) * 256;
        int l = tid & 63, w = tid >> 6;
        int rsub = l >> 2;
        int quad = l >> 4, l16 = l & 15;
        int wm = (w >> 1) * 32, wn = (w & 1) * 32;
        int rloc = w * 16 + rsub;
        int c = swz_src(rloc, l);
        const float* pz  = z2 + (size_t)(m0 + rloc) * D2 + k0 + c * 8;
        const float* pbi = b2 + k0 + c * 8;
        const unsigned short* pb = W3hi + (size_t)(n0 + rloc) * D2 + k0 + c * 8;
        ptrdiff_t dB = W3lo - W3hi;
        int aoff[2], boff[2];
        #pragma unroll
        for (int mt = 0; mt < 2; mt++) aoff[mt] = swz_frag(wm + mt * 16 + l16, quad);
        #pragma unroll
        for (int nt = 0; nt < 2; nt++) boff[nt] = swz_frag(wn + nt * 16 + l16, quad);
        int wrA = w * 512 + l * 8;
        f32x4 acc[2][2] = {};
        for (int kk = 0; kk < 256; kk += 32) {
            gld16(pb + kk,      sBh + w * 512);
            gld16(pb + dB + kk, sBl + w * 512);
            float4 za = *(const float4*)(pz + kk);
            float4 zb = *(const float4*)(pz + kk + 4);
            float4 ba = *(const float4*)(pbi + kk);
            float4 bb = *(const float4*)(pbi + kk + 4);
            float hv[8] = { za.x + ba.x, za.y + ba.y, za.z + ba.z, za.w + ba.w,
                            zb.x + bb.x, zb.y + bb.y, zb.z + bb.z, zb.w + bb.w };
            short8 h8, l8;
            #pragma unroll
            for (int q2 = 0; q2 < 8; q2++) {
                float h = hv[q2] > 0.f ? hv[q2] : 0.f;
                unsigned short hh = f2bf(h);
                h8[q2] = (short)hh;
                l8[q2] = (short)f2bf(h - bf2f(hh));
            }
            *(short8*)(sAh + wrA) = h8;
            *(short8*)(sAl + wrA) = l8;
            __syncthreads();
            short8 ah[2], al[2], bh[2], bl[2];
            #pragma unroll
            for (int mt = 0; mt < 2; mt++) {
                ah[mt] = *(const short8*)(sAh + aoff[mt]);
                al[mt] = *(const short8*)(sAl + aoff[mt]);
            }
            #pragma unroll
            for (int nt = 0; nt < 2; nt++) {
                bh[nt] = *(const short8*)(sBh + boff[nt]);
                bl[nt] = *(const short8*)(sBl + boff[nt]);
            }
            #pragma unroll
            for (int mt = 0; mt < 2; mt++)
                #pragma unroll
                for (int nt = 0; nt < 2; nt++) {
                    acc[mt][nt] = __builtin_amdgcn_mfma_f32_16x16x32_bf16(ah[mt], bh[nt], acc[mt][nt], 0, 0, 0);
                    acc[mt][nt] = __builtin_amdgcn_mfma_f32_16x16x32_bf16(ah[mt], bl[nt], acc[mt][nt], 0, 0, 0);
                    acc[mt][nt] = __builtin_amdgcn_mfma_f32_16x16x32_bf16(al[mt], bh[nt], acc[mt][nt], 0, 0, 0);
                }
            __syncthreads();
        }
        #pragma unroll
        for (int mt = 0; mt < 2; mt++)
            #pragma unroll
            for (int nt = 0; nt < 2; nt++) {
                int n = n0 + wn + nt * 16 + l16;
                #pragma unroll
                for (int r = 0; r < 4; r++) {
                    int m = m0 + wm + mt * 16 + quad * 4 + r;
                    atomicAdd(&z3[(size_t)m * D3 + n], acc[mt][nt][r]);
                }
            }
        return;
    }

    // ---- gemm2 (i8, BK=128): norm3; m2 mask from z2+b2 in LDS ----
    int j = bid - 32;
    signed char* As = (signed char*)smem;
    signed char* Bs = (signed char*)smem + 16384;
    unsigned char* mbuf = (unsigned char*)smem + 32768;  // 512 B
    int m0 = (j & 1) * 128;           // p
    int n0 = ((j >> 1) & 1) * 128;    // d
    int bc = j >> 2;                  // batch
    int l = tid & 63, w = tid >> 6;
    int quad = l >> 4, l16 = l & 15;
    int wm = (w >> 1) * 64, wn = (w & 1) * 64;
    const signed char* Bsrc = qV2 + (size_t)bc * (D * D2);

    {   // fill m2 mask row for this batch
        #pragma unroll
        for (int rr = 0; rr < 2; rr++) {
            int o = tid * 2 + rr;
            float z = z2[(size_t)bc * D2 + o] + b2[o];
            mbuf[o] = (z > 0.f) ? 0xFFu : 0u;
        }
    }
    __syncthreads();

    const signed char* pa[4];
    const signed char* pb[4];
    int lrow = l >> 3, ls = l & 7;
    #pragma unroll
    for (int r = 0; r < 4; r++) {
        int row = r * 32 + w * 8 + lrow;
        int c = (ls + (row & 7)) & 7;
        pa[r] = W3i8 + (size_t)(m0 + row) * D2 + c * 16;
        pb[r] = Bsrc + (size_t)(n0 + row) * D2 + c * 16;
    }
    int aoff[4][2], boff[4][2];
    #pragma unroll
    for (int mt = 0; mt < 4; mt++) {
        int tr = wm + mt * 16 + l16;
        #pragma unroll
        for (int ks = 0; ks < 2; ks++)
            aoff[mt][ks] = tr * 128 + (((ks * 4 + quad) - (tr & 7)) & 7) * 16;
    }
    #pragma unroll
    for (int nt = 0; nt < 4; nt++) {
        int tr = wn + nt * 16 + l16;
        #pragma unroll
        for (int ks = 0; ks < 2; ks++)
            boff[nt][ks] = tr * 128 + (((ks * 4 + quad) - (tr & 7)) & 7) * 16;
    }

    i32x4 acc[4][4];
    #pragma unroll
    for (int i = 0; i < 4; i++)
        #pragma unroll
        for (int jj = 0; jj < 4; jj++) acc[i][jj] = (i32x4)0;

    for (int kk = 0; kk < D2; kk += 128) {
        #pragma unroll
        for (int r = 0; r < 4; r++) {
            gld16(pa[r] + kk, As + r * 4096 + w * 1024);
            gld16(pb[r] + kk, Bs + r * 4096 + w * 1024);
        }
        __syncthreads();
        i32x4 mv0 = *(const i32x4*)(mbuf + kk + quad * 16);
        i32x4 mv1 = *(const i32x4*)(mbuf + kk + 64 + quad * 16);
        #pragma unroll
        for (int ks = 0; ks < 2; ks++) {
            i32x4 mv = ks ? mv1 : mv0;
            i32x4 a[4], bq[4];
            #pragma unroll
            for (int mt = 0; mt < 4; mt++)
                a[mt] = *(const i32x4*)(As + aoff[mt][ks]);
            #pragma unroll
            for (int nt = 0; nt < 4; nt++)
                bq[nt] = (*(const i32x4*)(Bs + boff[nt][ks])) & mv;
            #pragma unroll
            for (int mt = 0; mt < 4; mt++)
                #pragma unroll
                for (int nt = 0; nt < 4; nt++)
                    acc[mt][nt] = __builtin_amdgcn_mfma_i32_16x16x64_i8(
                        a[mt], bq[nt], acc[mt][nt], 0, 0, 0);
        }
        __syncthreads();
    }

    float saCQ[4];
    #pragma unroll
    for (int nt = 0; nt < 4; nt++)
        saCQ[nt] = saq[n0 + wn + nt * 16 + l16] * CQ;

    #pragma unroll
    for (int mt = 0; mt < 4; mt++)
        #pragma unroll
        for (int r = 0; r < 4; r++) {
            float s = 0.f;
            #pragma unroll
            for (int nt = 0; nt < 4; nt++) {
                float v = (float)acc[mt][nt][r] * saCQ[nt];
                s += v * v;
            }
            s += __shfl_down(s, 8, 64);
            s += __shfl_down(s, 4, 64);
            s += __shfl_down(s, 2, 64);
            s += __shfl_down(s, 1, 64);
            if (l16 == 0) {
                int p = m0 + wm + mt * 16 + quad * 4 + r;
                float s3 = s3q[p];
                atomicAdd(&norm3[(size_t)bc * D3 + p], s * s3 * s3);
            }
        }
}

// ---- wave-per-batch k-smallest sum (dist1 = |z1|/rn1 computed inline) ------
__global__ __launch_bounds__(256) void k_topk(
    const float* __restrict__ dists,    // [B][D1] |z1| only
    const float* __restrict__ rn1,      // [D1]
    const float* __restrict__ z2, const float* __restrict__ b2,
    const float* __restrict__ norm2,
    const float* __restrict__ z3, const float* __restrict__ b3,
    const float* __restrict__ norm3,
    const int* __restrict__ kp, float* __restrict__ outp) {
    int t = threadIdx.x;
    int wv = t >> 6, lane = t & 63;
    int b = blockIdx.x * 4 + wv;
    float lv[28];
    #pragma unroll
    for (int j = 0; j < 16; j++) {
        int n = lane + 64 * j;
        lv[j] = dists[(size_t)b * D1 + n] / rn1[n];
    }
    #pragma unroll
    for (int j = 16; j < 24; j++) {
        int o = lane + 64 * (j - 16);
        float zz = z2[(size_t)b * D2 + o] + b2[o];
        lv[j] = fabsf(zz) / sqrtf(norm2[(size_t)b * D2 + o]);
    }
    #pragma unroll
    for (int j = 24; j < 28; j++) {
        int p = lane + 64 * (j - 24);
        float zz = z3[(size_t)b * D3 + p] + b3[p];
        lv[j] = fabsf(zz) / sqrtf(norm3[(size_t)b * D3 + p]);
    }
    int k = *kp;
    if (k > NDIST) k = NDIST;
    float sum = 0.f;
    for (int it = 0; it < k; it++) {
        float mv = lv[0]; int mj = 0;
        #pragma unroll
        for (int j = 1; j < 28; j++)
            if (lv[j] < mv) { mv = lv[j]; mj = j; }
        unsigned long long key =
            ((unsigned long long)__float_as_uint(mv) << 32) | (unsigned)(lane * 32 + mj);
        #pragma unroll
        for (int off = 1; off < 64; off <<= 1) {
            unsigned long long o = __shfl_xor(key, off, 64);
            if (o < key) key = o;
        }
        sum += __uint_as_float((unsigned)(key >> 32));
        int wl = (int)((key >> 5) & 63u), wj = (int)(key & 31u);
        if (lane == wl) lv[wj] = FLT_MAX;
    }
    if (lane == 0) atomicAdd(outp, sum);
}

extern "C" void kernel_launch(void* const* d_in, const int* in_sizes, int n_in,
                              void* d_out, int out_size, void* d_ws, size_t ws_size,
                              hipStream_t stream) {
    const float* x  = (const float*)d_in[0];
    const float* W1 = (const float*)d_in[1];
    const float* b1 = (const float*)d_in[2];
    const float* W2 = (const float*)d_in[3];
    const float* b2 = (const float*)d_in[4];
    const float* W3 = (const float*)d_in[5];
    const float* b3 = (const float*)d_in[6];
    const int*   kp = (const int*)d_in[7];
    float* outp = (float*)d_out;

    float* fp = (float*)d_ws;
    float* rn1     = fp;                          fp += D1;
    float* dists   = fp;                          fp += (size_t)B * D1;
    float* saq     = fp;                          fp += D;
    float* sbq     = fp;                          fp += D2;
    float* s3q     = fp;                          fp += D3;
    // zero region: z2 || z3 || norm2 || norm3 (contiguous, 393216 floats)
    float* z2      = fp;                          fp += (size_t)B * D2;
    float* z3      = fp;                          fp += (size_t)B * D3;
    float* norm2   = fp;                          fp += (size_t)B * D2;
    float* norm3   = fp;                          fp += (size_t)B * D3;
    unsigned short* up = (unsigned short*)fp;
    unsigned short* W2hi  = up;  up += (size_t)D2 * D1;
    unsigned short* W2lo  = up;  up += (size_t)D2 * D1;
    unsigned short* W3hi  = up;  up += (size_t)D3 * D2;
    unsigned short* W3lo  = up;  up += (size_t)D3 * D2;
    unsigned short* h1hi  = up;  up += (size_t)B * D1;
    unsigned short* h1lo  = up;  up += (size_t)B * D1;
    signed char*    cp = (signed char*)up;
    signed char*    W1Ti8 = cp;  cp += (size_t)D * D1;
    signed char*    W2i8  = cp;  cp += (size_t)D2 * D1;
    signed char*    W3i8  = cp;  cp += (size_t)D3 * D2;
    unsigned char*  m1q   = (unsigned char*)cp;  cp += (size_t)B * D1;
    signed char*    qV2   = cp;   // full 256-batch (33.5 MB; ws proven since R10)

    // l1 gemm (64) + zeros (384) + W1 quant (32) + fused W2 quant+split (128)
    // + fused W3 quant+split (64) + rn1 (256) = 928 blocks
    k_l1p<<<928, 256, 0, stream>>>(x, W1, W2, W3, b1,
                                   dists, m1q, h1hi, h1lo,
                                   z2, outp, W2hi, W2lo, W3hi, W3lo,
                                   W1Ti8, saq, W2i8, sbq, W3i8, s3q, rn1);

    // l2a (128) || gemm1 (1024, 128d x 64o, G=4, counted-vmcnt dbuf, A-mask)
    k_big1<<<1152, 256, 0, stream>>>(h1hi, h1lo, W2hi, W2lo, z2,
                                     W1Ti8, W2i8, m1q, saq, sbq, qV2, norm2);

    // l3a z2-direct (32) || gemm2 single-buffer (R5 exact)
    k_big2<<<1056, 256, 0, stream>>>(z2, b2, W3hi, W3lo, z3,
                                     W3i8, qV2, saq, s3q, norm3);

    k_topk<<<B / 4, 256, 0, stream>>>(dists, rn1, z2, b2, norm2, z3, b3, norm3,
                                      kp, outp);
}

// Round 25
// 157.573 us; speedup vs baseline: 1.0241x; 1.0153x over previous
//
#include <hip/hip_runtime.h>
#include <math.h>
#include <float.h>

#define B   256
#define D   256
#define D1  1024
#define D2  512
#define D3  256
#define NDIST (D1 + D2 + D3)   // 1792
#define CQ  2.0f               // qV2 static scale multiplier (step = sa[d]*CQ)

typedef __attribute__((ext_vector_type(8))) short short8;
typedef __attribute__((ext_vector_type(4))) float f32x4;
typedef __attribute__((ext_vector_type(4))) int   i32x4;

__device__ __forceinline__ float waveReduceSum(float v) {
    #pragma unroll
    for (int off = 32; off > 0; off >>= 1)
        v += __shfl_down(v, off, 64);
    return v;
}
__device__ __forceinline__ float waveReduceMax(float v) {
    #pragma unroll
    for (int off = 32; off > 0; off >>= 1)
        v = fmaxf(v, __shfl_down(v, off, 64));
    return v;
}
__device__ __forceinline__ unsigned short f2bf(float f) {
    unsigned int u = __float_as_uint(f);
    u = (u + 0x7FFFu + ((u >> 16) & 1u)) >> 16;   // RNE
    return (unsigned short)u;
}
__device__ __forceinline__ float bf2f(unsigned short h) {
    return __uint_as_float(((unsigned int)h) << 16);
}
__device__ __forceinline__ void gld16(const void* g, void* l) {
    __builtin_amdgcn_global_load_lds(
        (const __attribute__((address_space(1))) unsigned int*)g,
        (__attribute__((address_space(3))) unsigned int*)l, 16, 0, 0);
}
__device__ __forceinline__ int swz_src(int row, int lane) {
    return ((lane & 3) + ((row >> 1) & 3)) & 3;
}
__device__ __forceinline__ int swz_frag(int row, int quad) {
    return row * 32 + (((quad - ((row >> 1) & 3)) & 3) * 8);
}

// load 8 fp32, split to bf16 hi/lo short8
__device__ __forceinline__ void split8(const float* p, short8& h8, short8& l8) {
    float4 a = *(const float4*)(p);
    float4 b = *(const float4*)(p + 4);
    float hv[8] = { a.x, a.y, a.z, a.w, b.x, b.y, b.z, b.w };
    #pragma unroll
    for (int q = 0; q < 8; q++) {
        unsigned short hh = f2bf(hv[q]);
        h8[q] = (short)hh;
        l8[q] = (short)f2bf(hv[q] - bf2f(hh));
    }
}

// ---- compensated bf16 MFMA mainloop, 64x64 tile, K range [k0, k0+KL) -------
template <int KD, int KL>
__device__ __forceinline__ void mfma3_64(
    const unsigned short* __restrict__ Ahi, const unsigned short* __restrict__ Alo,
    const unsigned short* __restrict__ Bhi, const unsigned short* __restrict__ Blo,
    int m0, int n0, int k0, unsigned short* sm, f32x4 acc[2][2]) {
    int tid = threadIdx.x;
    int l = tid & 63, w = tid >> 6;
    int rsub = l >> 2;
    int quad = l >> 4, l16 = l & 15;
    int wm = (w >> 1) * 32, wn = (w & 1) * 32;
    unsigned short* sAh = sm;
    unsigned short* sAl = sm + 2048;
    unsigned short* sBh = sm + 4096;
    unsigned short* sBl = sm + 6144;
    ptrdiff_t dA = Alo - Ahi, dB = Blo - Bhi;
    int rloc = w * 16 + rsub;
    int c = swz_src(rloc, l);
    const unsigned short* pa = Ahi + (size_t)(m0 + rloc) * KD + k0 + c * 8;
    const unsigned short* pb = Bhi + (size_t)(n0 + rloc) * KD + k0 + c * 8;
    int aoff[2], boff[2];
    #pragma unroll
    for (int mt = 0; mt < 2; mt++) aoff[mt] = swz_frag(wm + mt * 16 + l16, quad);
    #pragma unroll
    for (int nt = 0; nt < 2; nt++) boff[nt] = swz_frag(wn + nt * 16 + l16, quad);
    for (int kk = 0; kk < KL; kk += 32) {
        gld16(pa + kk,      sAh + w * 512);
        gld16(pa + dA + kk, sAl + w * 512);
        gld16(pb + kk,      sBh + w * 512);
        gld16(pb + dB + kk, sBl + w * 512);
        __syncthreads();
        short8 ah[2], al[2], bh[2], bl[2];
        #pragma unroll
        for (int mt = 0; mt < 2; mt++) {
            ah[mt] = *(const short8*)(sAh + aoff[mt]);
            al[mt] = *(const short8*)(sAl + aoff[mt]);
        }
        #pragma unroll
        for (int nt = 0; nt < 2; nt++) {
            bh[nt] = *(const short8*)(sBh + boff[nt]);
            bl[nt] = *(const short8*)(sBl + boff[nt]);
        }
        #pragma unroll
        for (int mt = 0; mt < 2; mt++)
            #pragma unroll
            for (int nt = 0; nt < 2; nt++) {
                acc[mt][nt] = __builtin_amdgcn_mfma_f32_16x16x32_bf16(ah[mt], bh[nt], acc[mt][nt], 0, 0, 0);
                acc[mt][nt] = __builtin_amdgcn_mfma_f32_16x16x32_bf16(ah[mt], bl[nt], acc[mt][nt], 0, 0, 0);
                acc[mt][nt] = __builtin_amdgcn_mfma_f32_16x16x32_bf16(al[mt], bh[nt], acc[mt][nt], 0, 0, 0);
            }
        __syncthreads();
    }
}

// ---- dispatch 1: l1 gemm + zeros + fused quant+split jobs + rn1 ------------
__global__ __launch_bounds__(256) void k_l1p(
    const float* __restrict__ x, const float* __restrict__ W1,
    const float* __restrict__ W2, const float* __restrict__ W3,
    const float* __restrict__ b1,
    float* __restrict__ dists, unsigned char* __restrict__ m1q,
    unsigned short* __restrict__ h1hi, unsigned short* __restrict__ h1lo,
    float* __restrict__ zeros, float* __restrict__ outp,
    unsigned short* __restrict__ W2hi, unsigned short* __restrict__ W2lo,
    unsigned short* __restrict__ W3hi, unsigned short* __restrict__ W3lo,
    signed char* __restrict__ W1Ti8, float* __restrict__ saq,
    signed char* __restrict__ W2i8,  float* __restrict__ sbq,
    signed char* __restrict__ W3i8,  float* __restrict__ s3q,
    float* __restrict__ rn1) {
    __shared__ __align__(16) unsigned short sm[8192];
    int blk = blockIdx.x;
    int t = threadIdx.x;

    if (blk < 64) {          // l1: z1 GEMM; A=x, B=W1 staged fp32->hi/lo
        unsigned short* sAh = sm;
        unsigned short* sAl = sm + 2048;
        unsigned short* sBh = sm + 4096;
        unsigned short* sBl = sm + 6144;
        int m0 = (blk & 3) * 64, n0 = (blk >> 2) * 64;
        int l = t & 63, w = t >> 6;
        int rsub = l >> 2;
        int quad = l >> 4, l16 = l & 15;
        int wm = (w >> 1) * 32, wn = (w & 1) * 32;
        int rloc = w * 16 + rsub;
        int c = swz_src(rloc, l);
        const float* pax = x + (size_t)(m0 + rloc) * D + c * 8;
        const float* pbw = W1 + (size_t)(n0 + rloc) * D + c * 8;
        int aoff[2], boff[2];
        #pragma unroll
        for (int mt = 0; mt < 2; mt++) aoff[mt] = swz_frag(wm + mt * 16 + l16, quad);
        #pragma unroll
        for (int nt = 0; nt < 2; nt++) boff[nt] = swz_frag(wn + nt * 16 + l16, quad);
        int wrA = w * 512 + l * 8;
        f32x4 acc[2][2] = {};
        for (int kk = 0; kk < D; kk += 32) {
            short8 ha, la, hb, lb;
            split8(pax + kk, ha, la);
            split8(pbw + kk, hb, lb);
            *(short8*)(sAh + wrA) = ha;
            *(short8*)(sAl + wrA) = la;
            *(short8*)(sBh + wrA) = hb;
            *(short8*)(sBl + wrA) = lb;
            __syncthreads();
            short8 ah[2], al[2], bh[2], bl[2];
            #pragma unroll
            for (int mt = 0; mt < 2; mt++) {
                ah[mt] = *(const short8*)(sAh + aoff[mt]);
                al[mt] = *(const short8*)(sAl + aoff[mt]);
            }
            #pragma unroll
            for (int nt = 0; nt < 2; nt++) {
                bh[nt] = *(const short8*)(sBh + boff[nt]);
                bl[nt] = *(const short8*)(sBl + boff[nt]);
            }
            #pragma unroll
            for (int mt = 0; mt < 2; mt++)
                #pragma unroll
                for (int nt = 0; nt < 2; nt++) {
                    acc[mt][nt] = __builtin_amdgcn_mfma_f32_16x16x32_bf16(ah[mt], bh[nt], acc[mt][nt], 0, 0, 0);
                    acc[mt][nt] = __builtin_amdgcn_mfma_f32_16x16x32_bf16(ah[mt], bl[nt], acc[mt][nt], 0, 0, 0);
                    acc[mt][nt] = __builtin_amdgcn_mfma_f32_16x16x32_bf16(al[mt], bh[nt], acc[mt][nt], 0, 0, 0);
                }
            __syncthreads();
        }
        #pragma unroll
        for (int mt = 0; mt < 2; mt++)
            #pragma unroll
            for (int nt = 0; nt < 2; nt++) {
                int n = n0 + wn + nt * 16 + l16;
                float bv = b1[n];
                #pragma unroll
                for (int r = 0; r < 4; r++) {
                    int m = m0 + wm + mt * 16 + quad * 4 + r;
                    float z = acc[mt][nt][r] + bv;
                    size_t idx = (size_t)m * D1 + n;
                    dists[idx] = fabsf(z);          // rn1 division deferred to topk
                    m1q[idx] = (z > 0.f) ? 0xFFu : 0u;
                    float h = z > 0.f ? z : 0.f;
                    unsigned short hh = f2bf(h);
                    h1hi[idx] = hh;
                    h1lo[idx] = f2bf(h - bf2f(hh));
                }
            }
        return;
    }
    if (blk < 448) {                                   // zero region (float4)
        if (blk == 64 && t == 0) outp[0] = 0.f;
        int i4 = (blk - 64) * 1024 + t * 4;
        *(float4*)(zeros + i4) = make_float4(0.f, 0.f, 0.f, 0.f);
        return;
    }
    if (blk < 480) {                                   // W1 col quant -> W1Ti8
        int ty = t >> 5, tx = t & 31;
        int d = (blk - 448) * 8 + ty;
        float m = 0.f;
        for (int i = tx; i < D1; i += 32) m = fmaxf(m, fabsf(W1[(size_t)i * D + d]));
        #pragma unroll
        for (int off = 16; off > 0; off >>= 1) m = fmaxf(m, __shfl_down(m, off, 32));
        m = __shfl(m, 0, 32);
        m = fmaxf(m, 1e-20f);
        if (tx == 0) saq[d] = m / 127.f;
        float inv = 127.f / m;
        for (int i = tx; i < D1; i += 32) {
            int q = __float2int_rn(W1[(size_t)i * D + d] * inv);
            W1Ti8[(size_t)d * D1 + i] = (signed char)q;
        }
        return;
    }
    if (blk < 608) {                     // W2 row quant + bf16 split (fused)
        int o = (blk - 480) * 4 + (t >> 6);
        int l = t & 63;
        const float* row = W2 + (size_t)o * D1;
        float4 v[4];
        #pragma unroll
        for (int jj = 0; jj < 4; jj++) v[jj] = *(const float4*)(row + jj * 256 + l * 4);
        float m = 0.f;
        #pragma unroll
        for (int jj = 0; jj < 4; jj++)
            m = fmaxf(m, fmaxf(fmaxf(fabsf(v[jj].x), fabsf(v[jj].y)),
                               fmaxf(fabsf(v[jj].z), fabsf(v[jj].w))));
        m = waveReduceMax(m);
        m = __shfl(m, 0, 64);
        m = fmaxf(m, 1e-20f);
        if (l == 0) sbq[o] = m / 127.f;
        float inv = 127.f / m;
        #pragma unroll
        for (int jj = 0; jj < 4; jj++) {
            int base = jj * 256 + l * 4;
            int q0 = __float2int_rn(v[jj].x * inv);
            int q1 = __float2int_rn(v[jj].y * inv);
            int q2 = __float2int_rn(v[jj].z * inv);
            int q3 = __float2int_rn(v[jj].w * inv);
            unsigned int pk = (unsigned)(q0 & 255) | ((unsigned)(q1 & 255) << 8) |
                              ((unsigned)(q2 & 255) << 16) | ((unsigned)(q3 & 255) << 24);
            *(unsigned int*)(W2i8 + (size_t)o * D1 + base) = pk;
            ushort4 h, lo;
            h.x = f2bf(v[jj].x); lo.x = f2bf(v[jj].x - bf2f(h.x));
            h.y = f2bf(v[jj].y); lo.y = f2bf(v[jj].y - bf2f(h.y));
            h.z = f2bf(v[jj].z); lo.z = f2bf(v[jj].z - bf2f(h.z));
            h.w = f2bf(v[jj].w); lo.w = f2bf(v[jj].w - bf2f(h.w));
            *(ushort4*)(W2hi + (size_t)o * D1 + base) = h;
            *(ushort4*)(W2lo + (size_t)o * D1 + base) = lo;
        }
        return;
    }
    if (blk < 672) {                     // W3 row quant + bf16 split (fused)
        int p = (blk - 608) * 4 + (t >> 6);
        int l = t & 63;
        const float* row = W3 + (size_t)p * D2;
        float4 v[2];
        #pragma unroll
        for (int jj = 0; jj < 2; jj++) v[jj] = *(const float4*)(row + jj * 256 + l * 4);
        float m = 0.f;
        #pragma unroll
        for (int jj = 0; jj < 2; jj++)
            m = fmaxf(m, fmaxf(fmaxf(fabsf(v[jj].x), fabsf(v[jj].y)),
                               fmaxf(fabsf(v[jj].z), fabsf(v[jj].w))));
        m = waveReduceMax(m);
        m = __shfl(m, 0, 64);
        m = fmaxf(m, 1e-20f);
        if (l == 0) s3q[p] = m / 127.f;
        float inv = 127.f / m;
        #pragma unroll
        for (int jj = 0; jj < 2; jj++) {
            int base = jj * 256 + l * 4;
            int q0 = __float2int_rn(v[jj].x * inv);
            int q1 = __float2int_rn(v[jj].y * inv);
            int q2 = __float2int_rn(v[jj].z * inv);
            int q3 = __float2int_rn(v[jj].w * inv);
            unsigned int pk = (unsigned)(q0 & 255) | ((unsigned)(q1 & 255) << 8) |
                              ((unsigned)(q2 & 255) << 16) | ((unsigned)(q3 & 255) << 24);
            *(unsigned int*)(W3i8 + (size_t)p * D2 + base) = pk;
            ushort4 h, lo;
            h.x = f2bf(v[jj].x); lo.x = f2bf(v[jj].x - bf2f(h.x));
            h.y = f2bf(v[jj].y); lo.y = f2bf(v[jj].y - bf2f(h.y));
            h.z = f2bf(v[jj].z); lo.z = f2bf(v[jj].z - bf2f(h.z));
            h.w = f2bf(v[jj].w); lo.w = f2bf(v[jj].w - bf2f(h.w));
            *(ushort4*)(W3hi + (size_t)p * D2 + base) = h;
            *(ushort4*)(W3lo + (size_t)p * D2 + base) = lo;
        }
        return;
    }
    {                                                  // rn1 (256 blks, topk-only)
        int gw = (blk - 672) * 4 + (t >> 6);
        int lane = t & 63;
        const float* row = W1 + (size_t)gw * D;
        float s = 0.f;
        for (int tt = lane; tt < D; tt += 64) { float v = row[tt]; s += v * v; }
        s = waveReduceSum(s);
        if (lane == 0) rn1[gw] = sqrtf(s);
    }
}

// ---- merged dispatch 2: l2a (blocks 0..127) || gemm1 (128..1151) -----------
// gemm1: 128d x 64o, G=4 + counted-vmcnt dbuf, A-side mask (session best:
// ~45us k_big1, ~159us total). FROZEN — final configuration.
__global__ __launch_bounds__(256, 2) void k_big1(
    const unsigned short* __restrict__ h1hi, const unsigned short* __restrict__ h1lo,
    const unsigned short* __restrict__ W2hi, const unsigned short* __restrict__ W2lo,
    float* __restrict__ z2,
    const signed char* __restrict__ W1Ti8,   // [256][1024]  A rows (d)
    const signed char* __restrict__ W2i8,    // [512][1024]  B rows (o)
    const unsigned char* __restrict__ m1q,   // [B][1024]
    const float* __restrict__ saq,           // [256]
    const float* __restrict__ sbq,           // [512]
    signed char* __restrict__ qV2,           // [256][256][512] (d-major)
    float* __restrict__ norm2) {             // [B][512]
    __shared__ __align__(16) unsigned char smem[53248]; // 2x24K dbuf + 4K masks
    int bid = blockIdx.x;

    if (bid < 128) {
        // ---- l2a: split-K partial z2 (atomic; bias folded downstream) ----
        unsigned short* sm = (unsigned short*)smem;
        int m0 = (bid & 3) * 64, n0 = ((bid >> 2) & 7) * 64, k0 = (bid >> 5) * 256;
        f32x4 acc[2][2] = {};
        mfma3_64<D1, 256>(h1hi, h1lo, W2hi, W2lo, m0, n0, k0, sm, acc);
        int l = threadIdx.x & 63, w = threadIdx.x >> 6;
        int quad = l >> 4, l16 = l & 15;
        int wm = (w >> 1) * 32, wn = (w & 1) * 32;
        #pragma unroll
        for (int mt = 0; mt < 2; mt++)
            #pragma unroll
            for (int nt = 0; nt < 2; nt++) {
                int n = n0 + wn + nt * 16 + l16;
                #pragma unroll
                for (int r = 0; r < 4; r++) {
                    int m = m0 + wm + mt * 16 + quad * 4 + r;
                    atomicAdd(&z2[(size_t)m * D2 + n], acc[mt][nt][r]);
                }
            }
        return;
    }

    // ---- gemm1 (i8, BK=128, 128d x 64o, G=4; counted-vmcnt dbuf) ----
    int j = bid - 128;                 // 0..1023
    unsigned char* mbuf = (unsigned char*)smem + 49152;  // [4][1024] masks
    int m0 = (j & 1) * 128;           // d tile
    int o0 = ((j >> 1) & 7) * 64;     // o tile
    int b0 = (j >> 4) * 4;            // first batch of quad
    int tid = threadIdx.x;
    int l = tid & 63, w = tid >> 6;
    int quad = l >> 4, l16 = l & 15;
    int wm = (w >> 1) * 64, wn = (w & 1) * 32;

    // stage 4 batches' mask rows (4 KB over 256 threads, 16 B each)
    *(int4*)(mbuf + tid * 16) = *(const int4*)(m1q + (size_t)b0 * D1 + tid * 16);

    const signed char* pa[4];
    const signed char* pb[2];
    int lrow = l >> 3, ls = l & 7;
    #pragma unroll
    for (int r = 0; r < 4; r++) {
        int row = r * 32 + w * 8 + lrow;
        int c = (ls + (row & 7)) & 7;
        pa[r] = W1Ti8 + (size_t)(m0 + row) * D1 + c * 16;
    }
    #pragma unroll
    for (int r = 0; r < 2; r++) {
        int row = r * 32 + w * 8 + lrow;
        int c = (ls + (row & 7)) & 7;
        pb[r] = W2i8 + (size_t)(o0 + row) * D1 + c * 16;
    }
    int aoff[4][2], boff[2][2];
    #pragma unroll
    for (int mt = 0; mt < 4; mt++) {
        int tr = wm + mt * 16 + l16;
        #pragma unroll
        for (int ks = 0; ks < 2; ks++)
            aoff[mt][ks] = tr * 128 + (((ks * 4 + quad) - (tr & 7)) & 7) * 16;
    }
    #pragma unroll
    for (int nt = 0; nt < 2; nt++) {
        int tr = wn + nt * 16 + l16;
        #pragma unroll
        for (int ks = 0; ks < 2; ks++)
            boff[nt][ks] = tr * 128 + (((ks * 4 + quad) - (tr & 7)) & 7) * 16;
    }

    i32x4 acc[4][4][2];
    #pragma unroll
    for (int g = 0; g < 4; g++)
        #pragma unroll
        for (int i = 0; i < 4; i++)
            #pragma unroll
            for (int jj = 0; jj < 2; jj++) acc[g][i][jj] = (i32x4)0;

    // prologue: tile 0 -> buf0; masks staged; one full drain
    {
        signed char* buf0 = (signed char*)smem;
        #pragma unroll
        for (int r = 0; r < 4; r++)
            gld16(pa[r], buf0 + r * 4096 + w * 1024);
        #pragma unroll
        for (int r = 0; r < 2; r++)
            gld16(pb[r], buf0 + 16384 + r * 4096 + w * 1024);
    }
    __syncthreads();

    for (int t = 0; t < 8; t++) {
        const signed char* bufc = (const signed char*)smem + (t & 1) * 24576;
        signed char* bufn = (signed char*)smem + ((t + 1) & 1) * 24576;
        if (t < 7) {
            int kn = (t + 1) * 128;
            #pragma unroll
            for (int r = 0; r < 4; r++)
                gld16(pa[r] + kn, bufn + r * 4096 + w * 1024);
            #pragma unroll
            for (int r = 0; r < 2; r++)
                gld16(pb[r] + kn, bufn + 16384 + r * 4096 + w * 1024);
            asm volatile("s_waitcnt vmcnt(6)" ::: "memory");
        } else {
            asm volatile("s_waitcnt vmcnt(0)" ::: "memory");
        }
        __builtin_amdgcn_s_barrier();       // all waves' tile-t loads landed
        __builtin_amdgcn_sched_barrier(0);  // pin: no ds_read hoisted above
        const signed char* As = bufc;
        const signed char* Bs = bufc + 16384;
        #pragma unroll
        for (int ks = 0; ks < 2; ks++) {
            i32x4 mv[4];
            #pragma unroll
            for (int g = 0; g < 4; g++)
                mv[g] = *(const i32x4*)(mbuf + g * 1024 + t * 128 + ks * 64 + quad * 16);
            i32x4 a[4], bq[2];
            #pragma unroll
            for (int mt = 0; mt < 4; mt++)
                a[mt] = *(const i32x4*)(As + aoff[mt][ks]);
            #pragma unroll
            for (int nt = 0; nt < 2; nt++)
                bq[nt] = *(const i32x4*)(Bs + boff[nt][ks]);
            #pragma unroll
            for (int g = 0; g < 4; g++) {
                #pragma unroll
                for (int mt = 0; mt < 4; mt++) {
                    i32x4 ag = a[mt] & mv[g];
                    #pragma unroll
                    for (int nt = 0; nt < 2; nt++)
                        acc[g][mt][nt] = __builtin_amdgcn_mfma_i32_16x16x64_i8(
                            ag, bq[nt], acc[g][mt][nt], 0, 0, 0);
                }
            }
        }
        // all reads of bufc complete (in regs) before any wave issues the
        // iter t+1 DMA writes that target this buffer
        __builtin_amdgcn_s_barrier();
    }

    // ---- fused epilogue per batch: single-pass cvt, sbv^2 factored out ----
    float sad[4][4];
    #pragma unroll
    for (int mt = 0; mt < 4; mt++)
        #pragma unroll
        for (int r = 0; r < 4; r++)
            sad[mt][r] = saq[m0 + wm + mt * 16 + quad * 4 + r];
    float sbv[2], sbdq[2];
    #pragma unroll
    for (int nt = 0; nt < 2; nt++) {
        sbv[nt] = sbq[o0 + wn + nt * 16 + l16];
        sbdq[nt] = sbv[nt] * (1.0f / CQ);
    }

    #pragma unroll
    for (int g = 0; g < 4; g++) {
        int bg = b0 + g;
        float nrm[2] = {0.f, 0.f};
        signed char* qb = qV2 + (size_t)bg * (D * D2);
        #pragma unroll
        for (int mt = 0; mt < 4; mt++) {
            int dbase = m0 + wm + mt * 16 + quad * 4;
            #pragma unroll
            for (int r = 0; r < 4; r++) {
                float sa = sad[mt][r];
                size_t rowoff = (size_t)(dbase + r) * D2;
                #pragma unroll
                for (int nt = 0; nt < 2; nt++) {
                    float tv = (float)acc[g][mt][nt][r];
                    float u = tv * sa;
                    nrm[nt] = fmaf(u, u, nrm[nt]);
                    int qi = __float2int_rn(tv * sbdq[nt]);
                    qi = max(-127, min(127, qi));
                    qb[rowoff + o0 + wn + nt * 16 + l16] = (signed char)qi;
                }
            }
        }
        #pragma unroll
        for (int nt = 0; nt < 2; nt++) {
            float s = nrm[nt] * (sbv[nt] * sbv[nt]);
            s += __shfl_down(s, 32, 64);
            s += __shfl_down(s, 16, 64);
            if (l < 16)
                atomicAdd(&norm2[(size_t)bg * D2 + o0 + wn + nt * 16 + l], s);
        }
    }
}

// ---- merged dispatch 3: l3a z2-direct (0..31) || gemm2 (32..1055) ----------
// (R5 exact: single-buffer 33 KB — proven best; frozen)
__global__ __launch_bounds__(256) void k_big2(
    const float* __restrict__ z2,            // [B][512] (bias NOT applied)
    const float* __restrict__ b2,            // [512]
    const unsigned short* __restrict__ W3hi, const unsigned short* __restrict__ W3lo,
    float* __restrict__ z3,
    const signed char* __restrict__ W3i8,    // [256][512]
    const signed char* __restrict__ qV2,     // [256][256][512]
    const float* __restrict__ saq,           // [256]
    const float* __restrict__ s3q,           // [256]
    float* __restrict__ norm3) {             // [B][256]
    __shared__ __align__(16) unsigned char smem[33280];  // 32K tiles + 512B mask
    int bid = blockIdx.x;
    int tid = threadIdx.x;

    if (bid < 32) {
        // ---- l3a: split-K partial z3; A = relu(z2+b2) hi/lo computed inline
        unsigned short* sAh = (unsigned short*)smem;
        unsigned short* sAl = sAh + 2048;
        unsigned short* sBh = sAh + 4096;
        unsigned short* sBl = sAh + 6144;
        int m0 = (bid & 3) * 64, n0 = ((bid >> 2) & 3) * 64, k0 = (bid >> 4) * 256;
        int l = tid & 63, w = tid >> 6;
        int rsub = l >> 2;
        int quad = l >> 4, l16 = l & 15;
        int wm = (w >> 1) * 32, wn = (w & 1) * 32;
        int rloc = w * 16 + rsub;
        int c = swz_src(rloc, l);
        const float* pz  = z2 + (size_t)(m0 + rloc) * D2 + k0 + c * 8;
        const float* pbi = b2 + k0 + c * 8;
        const unsigned short* pb = W3hi + (size_t)(n0 + rloc) * D2 + k0 + c * 8;
        ptrdiff_t dB = W3lo - W3hi;
        int aoff[2], boff[2];
        #pragma unroll
        for (int mt = 0; mt < 2; mt++) aoff[mt] = swz_frag(wm + mt * 16 + l16, quad);
        #pragma unroll
        for (int nt = 0; nt < 2; nt++) boff[nt] = swz_frag(wn + nt * 16 + l16, quad);
        int wrA = w * 512 + l * 8;
        f32x4 acc[2][2] = {};
        for (int kk = 0; kk < 256; kk += 32) {
            gld16(pb + kk,      sBh + w * 512);
            gld16(pb + dB + kk, sBl + w * 512);
            float4 za = *(const float4*)(pz + kk);
            float4 zb = *(const float4*)(pz + kk + 4);
            float4 ba = *(const float4*)(pbi + kk);
            float4 bb = *(const float4*)(pbi + kk + 4);
            float hv[8] = { za.x + ba.x, za.y + ba.y, za.z + ba.z, za.w + ba.w,
                            zb.x + bb.x, zb.y + bb.y, zb.z + bb.z, zb.w + bb.w };
            short8 h8, l8;
            #pragma unroll
            for (int q2 = 0; q2 < 8; q2++) {
                float h = hv[q2] > 0.f ? hv[q2] : 0.f;
                unsigned short hh = f2bf(h);
                h8[q2] = (short)hh;
                l8[q2] = (short)f2bf(h - bf2f(hh));
            }
            *(short8*)(sAh + wrA) = h8;
            *(short8*)(sAl + wrA) = l8;
            __syncthreads();
            short8 ah[2], al[2], bh[2], bl[2];
            #pragma unroll
            for (int mt = 0; mt < 2; mt++) {
                ah[mt] = *(const short8*)(sAh + aoff[mt]);
                al[mt] = *(const short8*)(sAl + aoff[mt]);
            }
            #pragma unroll
            for (int nt = 0; nt < 2; nt++) {
                bh[nt] = *(const short8*)(sBh + boff[nt]);
                bl[nt] = *(const short8*)(sBl + boff[nt]);
            }
            #pragma unroll
            for (int mt = 0; mt < 2; mt++)
                #pragma unroll
                for (int nt = 0; nt < 2; nt++) {
                    acc[mt][nt] = __builtin_amdgcn_mfma_f32_16x16x32_bf16(ah[mt], bh[nt], acc[mt][nt], 0, 0, 0);
                    acc[mt][nt] = __builtin_amdgcn_mfma_f32_16x16x32_bf16(ah[mt], bl[nt], acc[mt][nt], 0, 0, 0);
                    acc[mt][nt] = __builtin_amdgcn_mfma_f32_16x16x32_bf16(al[mt], bh[nt], acc[mt][nt], 0, 0, 0);
                }
            __syncthreads();
        }
        #pragma unroll
        for (int mt = 0; mt < 2; mt++)
            #pragma unroll
            for (int nt = 0; nt < 2; nt++) {
                int n = n0 + wn + nt * 16 + l16;
                #pragma unroll
                for (int r = 0; r < 4; r++) {
                    int m = m0 + wm + mt * 16 + quad * 4 + r;
                    atomicAdd(&z3[(size_t)m * D3 + n], acc[mt][nt][r]);
                }
            }
        return;
    }

    // ---- gemm2 (i8, BK=128): norm3; m2 mask from z2+b2 in LDS ----
    int j = bid - 32;
    signed char* As = (signed char*)smem;
    signed char* Bs = (signed char*)smem + 16384;
    unsigned char* mbuf = (unsigned char*)smem + 32768;  // 512 B
    int m0 = (j & 1) * 128;           // p
    int n0 = ((j >> 1) & 1) * 128;    // d
    int bc = j >> 2;                  // batch
    int l = tid & 63, w = tid >> 6;
    int quad = l >> 4, l16 = l & 15;
    int wm = (w >> 1) * 64, wn = (w & 1) * 64;
    const signed char* Bsrc = qV2 + (size_t)bc * (D * D2);

    {   // fill m2 mask row for this batch
        #pragma unroll
        for (int rr = 0; rr < 2; rr++) {
            int o = tid * 2 + rr;
            float z = z2[(size_t)bc * D2 + o] + b2[o];
            mbuf[o] = (z > 0.f) ? 0xFFu : 0u;
        }
    }
    __syncthreads();

    const signed char* pa[4];
    const signed char* pb[4];
    int lrow = l >> 3, ls = l & 7;
    #pragma unroll
    for (int r = 0; r < 4; r++) {
        int row = r * 32 + w * 8 + lrow;
        int c = (ls + (row & 7)) & 7;
        pa[r] = W3i8 + (size_t)(m0 + row) * D2 + c * 16;
        pb[r] = Bsrc + (size_t)(n0 + row) * D2 + c * 16;
    }
    int aoff[4][2], boff[4][2];
    #pragma unroll
    for (int mt = 0; mt < 4; mt++) {
        int tr = wm + mt * 16 + l16;
        #pragma unroll
        for (int ks = 0; ks < 2; ks++)
            aoff[mt][ks] = tr * 128 + (((ks * 4 + quad) - (tr & 7)) & 7) * 16;
    }
    #pragma unroll
    for (int nt = 0; nt < 4; nt++) {
        int tr = wn + nt * 16 + l16;
        #pragma unroll
        for (int ks = 0; ks < 2; ks++)
            boff[nt][ks] = tr * 128 + (((ks * 4 + quad) - (tr & 7)) & 7) * 16;
    }

    i32x4 acc[4][4];
    #pragma unroll
    for (int i = 0; i < 4; i++)
        #pragma unroll
        for (int jj = 0; jj < 4; jj++) acc[i][jj] = (i32x4)0;

    for (int kk = 0; kk < D2; kk += 128) {
        #pragma unroll
        for (int r = 0; r < 4; r++) {
            gld16(pa[r] + kk, As + r * 4096 + w * 1024);
            gld16(pb[r] + kk, Bs + r * 4096 + w * 1024);
        }
        __syncthreads();
        i32x4 mv0 = *(const i32x4*)(mbuf + kk + quad * 16);
        i32x4 mv1 = *(const i32x4*)(mbuf + kk + 64 + quad * 16);
        #pragma unroll
        for (int ks = 0; ks < 2; ks++) {
            i32x4 mv = ks ? mv1 : mv0;
            i32x4 a[4], bq[4];
            #pragma unroll
            for (int mt = 0; mt < 4; mt++)
                a[mt] = *(const i32x4*)(As + aoff[mt][ks]);
            #pragma unroll
            for (int nt = 0; nt < 4; nt++)
                bq[nt] = (*(const i32x4*)(Bs + boff[nt][ks])) & mv;
            #pragma unroll
            for (int mt = 0; mt < 4; mt++)
                #pragma unroll
                for (int nt = 0; nt < 4; nt++)
                    acc[mt][nt] = __builtin_amdgcn_mfma_i32_16x16x64_i8(
                        a[mt], bq[nt], acc[mt][nt], 0, 0, 0);
        }
        __syncthreads();
    }

    float saCQ[4];
    #pragma unroll
    for (int nt = 0; nt < 4; nt++)
        saCQ[nt] = saq[n0 + wn + nt * 16 + l16] * CQ;

    #pragma unroll
    for (int mt = 0; mt < 4; mt++)
        #pragma unroll
        for (int r = 0; r < 4; r++) {
            float s = 0.f;
            #pragma unroll
            for (int nt = 0; nt < 4; nt++) {
                float v = (float)acc[mt][nt][r] * saCQ[nt];
                s += v * v;
            }
            s += __shfl_down(s, 8, 64);
            s += __shfl_down(s, 4, 64);
            s += __shfl_down(s, 2, 64);
            s += __shfl_down(s, 1, 64);
            if (l16 == 0) {
                int p = m0 + wm + mt * 16 + quad * 4 + r;
                float s3 = s3q[p];
                atomicAdd(&norm3[(size_t)bc * D3 + p], s * s3 * s3);
            }
        }
}

// ---- wave-per-batch k-smallest sum (dist1 = |z1|/rn1 computed inline) ------
__global__ __launch_bounds__(256) void k_topk(
    const float* __restrict__ dists,    // [B][D1] |z1| only
    const float* __restrict__ rn1,      // [D1]
    const float* __restrict__ z2, const float* __restrict__ b2,
    const float* __restrict__ norm2,
    const float* __restrict__ z3, const float* __restrict__ b3,
    const float* __restrict__ norm3,
    const int* __restrict__ kp, float* __restrict__ outp) {
    int t = threadIdx.x;
    int wv = t >> 6, lane = t & 63;
    int b = blockIdx.x * 4 + wv;
    float lv[28];
    #pragma unroll
    for (int j = 0; j < 16; j++) {
        int n = lane + 64 * j;
        lv[j] = dists[(size_t)b * D1 + n] / rn1[n];
    }
    #pragma unroll
    for (int j = 16; j < 24; j++) {
        int o = lane + 64 * (j - 16);
        float zz = z2[(size_t)b * D2 + o] + b2[o];
        lv[j] = fabsf(zz) / sqrtf(norm2[(size_t)b * D2 + o]);
    }
    #pragma unroll
    for (int j = 24; j < 28; j++) {
        int p = lane + 64 * (j - 24);
        float zz = z3[(size_t)b * D3 + p] + b3[p];
        lv[j] = fabsf(zz) / sqrtf(norm3[(size_t)b * D3 + p]);
    }
    int k = *kp;
    if (k > NDIST) k = NDIST;
    float sum = 0.f;
    for (int it = 0; it < k; it++) {
        float mv = lv[0]; int mj = 0;
        #pragma unroll
        for (int j = 1; j < 28; j++)
            if (lv[j] < mv) { mv = lv[j]; mj = j; }
        unsigned long long key =
            ((unsigned long long)__float_as_uint(mv) << 32) | (unsigned)(lane * 32 + mj);
        #pragma unroll
        for (int off = 1; off < 64; off <<= 1) {
            unsigned long long o = __shfl_xor(key, off, 64);
            if (o < key) key = o;
        }
        sum += __uint_as_float((unsigned)(key >> 32));
        int wl = (int)((key >> 5) & 63u), wj = (int)(key & 31u);
        if (lane == wl) lv[wj] = FLT_MAX;
    }
    if (lane == 0) atomicAdd(outp, sum);
}

extern "C" void kernel_launch(void* const* d_in, const int* in_sizes, int n_in,
                              void* d_out, int out_size, void* d_ws, size_t ws_size,
                              hipStream_t stream) {
    const float* x  = (const float*)d_in[0];
    const float* W1 = (const float*)d_in[1];
    const float* b1 = (const float*)d_in[2];
    const float* W2 = (const float*)d_in[3];
    const float* b2 = (const float*)d_in[4];
    const float* W3 = (const float*)d_in[5];
    const float* b3 = (const float*)d_in[6];
    const int*   kp = (const int*)d_in[7];
    float* outp = (float*)d_out;

    float* fp = (float*)d_ws;
    float* rn1     = fp;                          fp += D1;
    float* dists   = fp;                          fp += (size_t)B * D1;
    float* saq     = fp;                          fp += D;
    float* sbq     = fp;                          fp += D2;
    float* s3q     = fp;                          fp += D3;
    // zero region: z2 || z3 || norm2 || norm3 (contiguous, 393216 floats)
    float* z2      = fp;                          fp += (size_t)B * D2;
    float* z3      = fp;                          fp += (size_t)B * D3;
    float* norm2   = fp;                          fp += (size_t)B * D2;
    float* norm3   = fp;                          fp += (size_t)B * D3;
    unsigned short* up = (unsigned short*)fp;
    unsigned short* W2hi  = up;  up += (size_t)D2 * D1;
    unsigned short* W2lo  = up;  up += (size_t)D2 * D1;
    unsigned short* W3hi  = up;  up += (size_t)D3 * D2;
    unsigned short* W3lo  = up;  up += (size_t)D3 * D2;
    unsigned short* h1hi  = up;  up += (size_t)B * D1;
    unsigned short* h1lo  = up;  up += (size_t)B * D1;
    signed char*    cp = (signed char*)up;
    signed char*    W1Ti8 = cp;  cp += (size_t)D * D1;
    signed char*    W2i8  = cp;  cp += (size_t)D2 * D1;
    signed char*    W3i8  = cp;  cp += (size_t)D3 * D2;
    unsigned char*  m1q   = (unsigned char*)cp;  cp += (size_t)B * D1;
    signed char*    qV2   = cp;   // full 256-batch (33.5 MB; ws proven since R10)

    // l1 gemm (64) + zeros (384) + W1 quant (32) + fused W2 quant+split (128)
    // + fused W3 quant+split (64) + rn1 (256) = 928 blocks
    k_l1p<<<928, 256, 0, stream>>>(x, W1, W2, W3, b1,
                                   dists, m1q, h1hi, h1lo,
                                   z2, outp, W2hi, W2lo, W3hi, W3lo,
                                   W1Ti8, saq, W2i8, sbq, W3i8, s3q, rn1);

    // l2a (128) || gemm1 (1024, 128d x 64o, G=4, counted-vmcnt dbuf, A-mask)
    k_big1<<<1152, 256, 0, stream>>>(h1hi, h1lo, W2hi, W2lo, z2,
                                     W1Ti8, W2i8, m1q, saq, sbq, qV2, norm2);

    // l3a z2-direct (32) || gemm2 single-buffer (R5 exact)
    k_big2<<<1056, 256, 0, stream>>>(z2, b2, W3hi, W3lo, z3,
                                     W3i8, qV2, saq, s3q, norm3);

    k_topk<<<B / 4, 256, 0, stream>>>(dists, rn1, z2, b2, norm2, z3, b3, norm3,
                                      kp, outp);
}